// Round 12
// baseline (108.029 us; speedup 1.0000x reference)
//
#include <hip/hip_runtime.h>
#include <hip/hip_bf16.h>

#define B_ 4
#define S_ 2048
#define D_ 512
#define H_ 16
#define DK_ 32
#define MS_ 8192   // B_*S_

typedef unsigned short u16;
typedef __attribute__((ext_vector_type(4))) unsigned short u16x4;
typedef __attribute__((ext_vector_type(8))) short bf16x8;
typedef __attribute__((ext_vector_type(4))) float f32x4;

union pbu { unsigned u[4]; bf16x8 v; };

__device__ __forceinline__ u16 f2b(float f) {
    union { float f; unsigned u; } uf; uf.f = f;
    unsigned u = uf.u;
    unsigned r = u + 0x7fffu + ((u >> 16) & 1u);  // RNE
    return (u16)(r >> 16);
}

__device__ __forceinline__ unsigned cvt_pk_bf16(float lo, float hi) {
    unsigned r;
    asm("v_cvt_pk_bf16_f32 %0, %1, %2" : "=v"(r) : "v"(lo), "v"(hi));
    return r;
}

// async global->LDS, 16B per lane; dst is wave-uniform base, HW adds lane*16
__device__ __forceinline__ void gload16(const u16* src, u16* dst) {
    __builtin_amdgcn_global_load_lds(
        (const __attribute__((address_space(1))) unsigned int*)src,
        (__attribute__((address_space(3))) unsigned int*)dst, 16, 0, 0);
}

// ---------------- transpose+cast 4 weight matrices: WT[z][n][k] = W_z[k][n] ----------------
__global__ void transpose_cast(const float* __restrict__ Wq, const float* __restrict__ Wk,
                               const float* __restrict__ Wv, const float* __restrict__ Wo,
                               u16* __restrict__ out) {
    const int z = blockIdx.z;
    const float* W = (z == 0) ? Wq : (z == 1) ? Wk : (z == 2) ? Wv : Wo;
    u16* O = out + (size_t)z * D_ * D_;
    __shared__ float T[32][33];
    const int n0 = blockIdx.x * 32, k0 = blockIdx.y * 32;
    const int tx = threadIdx.x & 31, ty = threadIdx.x >> 5;
#pragma unroll
    for (int i = 0; i < 4; i++) {
        int row = ty + 8 * i;
        T[tx][row] = W[(size_t)(k0 + row) * D_ + n0 + tx];
    }
    __syncthreads();
#pragma unroll
    for (int i = 0; i < 4; i++) {
        int row = ty + 8 * i;
        O[(size_t)(n0 + row) * D_ + k0 + tx] = f2b(T[row][tx]);
    }
}

// ---------------- QKV GEMM: 128x128 tile, BK=64 ----------------
// A staged from f32 x with fused bf16 conversion (reg-stage, both-sides swizzle);
// B staged via global_load_lds + XOR swizzle. Q output pre-scaled by log2(e)/sqrt(32).
__launch_bounds__(256)
__global__ void gemm_qkv(const float* __restrict__ Xf, const u16* __restrict__ WT,
                         const float* __restrict__ bq, const float* __restrict__ bk, const float* __restrict__ bv,
                         u16* __restrict__ Qw, u16* __restrict__ Kw, u16* __restrict__ Vw) {
    const int which = blockIdx.z;
    const u16* Wt = WT + (size_t)which * D_ * D_;
    const float* bias = (which == 0) ? bq : (which == 1) ? bk : bv;
    u16* Out = (which == 0) ? Qw : (which == 1) ? Kw : Vw;
    const float oscale = (which == 0) ? (float)(1.4426950408889634 / 5.656854249492381) : 1.0f;

    __shared__ __attribute__((aligned(16))) u16 As[128][64];
    __shared__ __attribute__((aligned(16))) u16 Bs[128][64];

    const int tid = threadIdx.x;
    const int lane = tid & 63, w = tid >> 6;
    const int wr = w >> 1, wc = w & 1;
    const int g = lane >> 4, c = lane & 15;
    const int bm0 = blockIdx.y * 128, bn0 = blockIdx.x * 128;

    // invariant (both operands): LDS[row][gd] = global granule gd ^ (row&7)
    const int trow = tid >> 3;
    const int tcg = (tid & 7) ^ (trow & 7);     // source granule this thread loads
    const float* gAf = Xf + (size_t)(bm0 + trow) * D_ + 8 * tcg;   // f32 source
    const u16*   gB  = Wt + (size_t)(bn0 + trow) * D_ + 8 * tcg;

    f32x4 acc[4][4];
#pragma unroll
    for (int i = 0; i < 4; i++)
#pragma unroll
        for (int j = 0; j < 4; j++) acc[i][j] = (f32x4)0.0f;

    for (int k0 = 0; k0 < D_; k0 += 64) {
        // B: async gload16 (4 chunks of 32 rows)
#pragma unroll
        for (int i = 0; i < 4; i++)
            gload16(gB + (size_t)(32 * i) * D_ + k0, &Bs[0][0] + 512 * w + 2048 * i);
        // A: reg-stage f32 -> bf16, write dest granule tid&7 of row trow+32i
#pragma unroll
        for (int i = 0; i < 4; i++) {
            const float* src = gAf + (size_t)(32 * i) * D_ + k0;
            f32x4 lo = *(const f32x4*)src;
            f32x4 hi = *(const f32x4*)(src + 4);
            union { u16 s[8]; bf16x8 v; } pk;
#pragma unroll
            for (int j = 0; j < 4; j++) { pk.s[j] = f2b(lo[j]); pk.s[4 + j] = f2b(hi[j]); }
            *(bf16x8*)&As[trow + 32 * i][8 * (tid & 7)] = pk.v;
        }
        __syncthreads();   // drains vmcnt (B gload) + lgkm (A writes)
#pragma unroll
        for (int kk = 0; kk < 2; kk++) {
            bf16x8 a[4], b[4];
#pragma unroll
            for (int mi = 0; mi < 4; mi++)
                a[mi] = *(const bf16x8*)&As[wr * 64 + 16 * mi + c][8 * ((4 * kk + g) ^ (c & 7))];
#pragma unroll
            for (int ni = 0; ni < 4; ni++)
                b[ni] = *(const bf16x8*)&Bs[wc * 64 + 16 * ni + c][8 * ((4 * kk + g) ^ (c & 7))];
#pragma unroll
            for (int mi = 0; mi < 4; mi++)
#pragma unroll
                for (int ni = 0; ni < 4; ni++)
                    acc[mi][ni] = __builtin_amdgcn_mfma_f32_16x16x32_bf16(a[mi], b[ni], acc[mi][ni], 0, 0, 0);
        }
        __syncthreads();
    }
#pragma unroll
    for (int mi = 0; mi < 4; mi++)
#pragma unroll
        for (int ni = 0; ni < 4; ni++)
#pragma unroll
            for (int r = 0; r < 4; r++) {
                int m = bm0 + wr * 64 + 16 * mi + 4 * g + r;
                int n = bn0 + wc * 64 + 16 * ni + c;
                float v = (acc[mi][ni][r] + bias[n]) * oscale;
                int b = m >> 11, s = m & 2047;
                int h = n >> 5, dk = n & 31;
                Out[(((size_t)(b * H_ + h) * S_) + s) * DK_ + dk] = f2b(v);
            }
}

// ---------------- flash attention (r11-exact: r7 body + setprio) ----------------
// 256 q per block (8 waves x 32 q), KVBLK=128 (two verified 64-kv subtiles),
// single buffer, 2 barriers/tile, Q pre-scaled (exp2 direct), row-sum via ones-MFMA.
__launch_bounds__(512)
__global__ void attn_kernel(const u16* __restrict__ Q, const u16* __restrict__ K,
                            const u16* __restrict__ V, u16* __restrict__ O,
                            const int* __restrict__ mbp) {
    const int border = *mbp;
    const unsigned b2u = (unsigned)(2 * border);
    const int bh = blockIdx.x;          // all q-blocks of one bh -> same XCD (ids differ by 64)
    const int q0 = blockIdx.y * 256;
    const int tid = threadIdx.x;
    const int lane = tid & 63;
    const int w = __builtin_amdgcn_readfirstlane(tid >> 6);   // wave-uniform
    const int g = lane >> 4, c = lane & 15;

    __shared__ __attribute__((aligned(16))) u16 Ks[128][32];     // two permuted 64-row halves
    __shared__ __attribute__((aligned(16))) u16 Vt[2][32][68];   // [kv-half][dv][kk]

    const u16* Qbh = Q + (size_t)bh * S_ * DK_;
    const u16* Kbh = K + (size_t)bh * S_ * DK_;
    const u16* Vbh = V + (size_t)bh * S_ * DK_;

    const int qw0 = q0 + w * 32;        // wave-uniform
    const int qiA = qw0 + c;
    const int qiB = qw0 + 16 + c;
    const bf16x8 qfA = *(const bf16x8*)&Qbh[(size_t)qiA * DK_ + 8 * g];
    const bf16x8 qfB = *(const bf16x8*)&Qbh[(size_t)qiB * DK_ + 8 * g];

    f32x4 accO[2][2];   // [qs][dv-half]
    f32x4 accL[2];      // [qs] row-sum accumulator (all rows identical)
#pragma unroll
    for (int i = 0; i < 2; i++) { accO[i][0] = (f32x4)0.0f; accO[i][1] = (f32x4)0.0f; accL[i] = (f32x4)0.0f; }

    const float C2 = 1.4426950408889634f;   // log2(e) * 1.0 (band add, post-scale)

    // ones A-fragment for row-sum MFMA (constant -> layout-independent)
    union { u16x4 h[2]; bf16x8 v; } ones;
#pragma unroll
    for (int j = 0; j < 4; j++) { ones.h[0][j] = 0x3F80; ones.h[1][j] = 0x3F80; }

    // staging indices (round-2 verified): 512 thr x u16x4 covers one 64x32 tile
    const int skk = tid >> 3;
    const int sc4 = (tid & 7) << 2;
    const int srow = 32 * ((skk >> 2) & 1) + 16 * ((skk >> 5) & 1) + (((skk >> 3) & 3) << 2) + (skk & 3);

    // softmax+pack for one 16-q subtile vs one 64-kv subtile
    auto sm_pack = [&](const f32x4* sf, int qs0, int qiv, int kvs, pbu* pb) {
        float e[4][4];
        const bool aOut = (qs0 > kvs + 63 + border) || (qs0 + 15 + border < kvs);
        const bool aIn  = (qs0 + 15 <= kvs + border) && (kvs + 63 <= qs0 + border);
        if (aOut) {
#pragma unroll
            for (int ct = 0; ct < 4; ct++)
#pragma unroll
                for (int r = 0; r < 4; r++)
                    e[ct][r] = __builtin_amdgcn_exp2f(sf[ct][r]);
        } else if (aIn) {
#pragma unroll
            for (int ct = 0; ct < 4; ct++)
#pragma unroll
                for (int r = 0; r < 4; r++)
                    e[ct][r] = __builtin_amdgcn_exp2f(sf[ct][r] + C2);
        } else {
            const int qb = qiv + border - kvs;
#pragma unroll
            for (int ct = 0; ct < 4; ct++) {
                const int k0l = 32 * (ct & 1) + 8 * g + 4 * (ct >> 1);
#pragma unroll
                for (int r = 0; r < 4; r++) {
                    float a = ((unsigned)(qb - (k0l + r)) <= b2u) ? C2 : 0.0f;
                    e[ct][r] = __builtin_amdgcn_exp2f(sf[ct][r] + a);
                }
            }
        }
        // pack (round-2 verified ordering)
        pb[0].u[0] = cvt_pk_bf16(e[0][0], e[0][1]);
        pb[0].u[1] = cvt_pk_bf16(e[0][2], e[0][3]);
        pb[0].u[2] = cvt_pk_bf16(e[2][0], e[2][1]);
        pb[0].u[3] = cvt_pk_bf16(e[2][2], e[2][3]);
        pb[1].u[0] = cvt_pk_bf16(e[1][0], e[1][1]);
        pb[1].u[1] = cvt_pk_bf16(e[1][2], e[1][3]);
        pb[1].u[2] = cvt_pk_bf16(e[3][0], e[3][1]);
        pb[1].u[3] = cvt_pk_bf16(e[3][2], e[3][3]);
    };

    // one 64-kv subtile: QK^T (both q-subtiles) -> softmax -> PV + row-sum MFMA
    auto do_sub = [&](int sub, int kvs) {
        f32x4 sA[4], sB[4];
#pragma unroll
        for (int ct = 0; ct < 4; ct++) {
            const bf16x8 kf = *(const bf16x8*)&Ks[sub * 64 + 16 * ct + c][8 * g];
            sA[ct] = __builtin_amdgcn_mfma_f32_16x16x32_bf16(kf, qfA, (f32x4)0.0f, 0, 0, 0);
            sB[ct] = __builtin_amdgcn_mfma_f32_16x16x32_bf16(kf, qfB, (f32x4)0.0f, 0, 0, 0);
        }
        pbu pA[2], pB[2];
        sm_pack(sA, qw0, qiA, kvs, pA);
        sm_pack(sB, qw0 + 16, qiB, kvs, pB);
#pragma unroll
        for (int t2 = 0; t2 < 2; t2++) {
#pragma unroll
            for (int ksl = 0; ksl < 2; ksl++) {
                union { u16x4 h[2]; bf16x8 v; } vf;
                vf.h[0] = *(const u16x4*)&Vt[sub][16 * t2 + c][32 * ksl + 8 * g];
                vf.h[1] = *(const u16x4*)&Vt[sub][16 * t2 + c][32 * ksl + 8 * g + 4];
                accO[0][t2] = __builtin_amdgcn_mfma_f32_16x16x32_bf16(vf.v, pA[ksl].v, accO[0][t2], 0, 0, 0);
                accO[1][t2] = __builtin_amdgcn_mfma_f32_16x16x32_bf16(vf.v, pB[ksl].v, accO[1][t2], 0, 0, 0);
            }
        }
#pragma unroll
        for (int ksl = 0; ksl < 2; ksl++) {
            accL[0] = __builtin_amdgcn_mfma_f32_16x16x32_bf16(ones.v, pA[ksl].v, accL[0], 0, 0, 0);
            accL[1] = __builtin_amdgcn_mfma_f32_16x16x32_bf16(ones.v, pB[ksl].v, accL[1], 0, 0, 0);
        }
    };

    for (int kv0 = 0; kv0 < S_; kv0 += 128) {
        // stage both K halves (permuted rows) + both V^T halves (r7-verified, single buffer)
        *(u16x4*)&Ks[srow][sc4]      = *(const u16x4*)&Kbh[(size_t)(kv0 + skk) * DK_ + sc4];
        *(u16x4*)&Ks[64 + srow][sc4] = *(const u16x4*)&Kbh[(size_t)(kv0 + 64 + skk) * DK_ + sc4];
        u16x4 va = *(const u16x4*)&Vbh[(size_t)(kv0 + skk) * DK_ + sc4];
        u16x4 vb = *(const u16x4*)&Vbh[(size_t)(kv0 + 64 + skk) * DK_ + sc4];
#pragma unroll
        for (int j = 0; j < 4; j++) {
            Vt[0][sc4 + j][skk] = va[j];
            Vt[1][sc4 + j][skk] = vb[j];
        }
        __syncthreads();

        __builtin_amdgcn_s_setprio(1);
        do_sub(0, kv0);
        do_sub(1, kv0 + 64);
        __builtin_amdgcn_s_setprio(0);

        __syncthreads();
    }

    // epilogue: l from accL (all rows equal; col c corresponds to this lane's q)
    const int b = bh >> 4, h = bh & 15;
    const float linvA = 1.0f / accL[0][0];
    const float linvB = 1.0f / accL[1][0];
#pragma unroll
    for (int t2 = 0; t2 < 2; t2++) {
        u16x4 oA, oB;
#pragma unroll
        for (int r = 0; r < 4; r++) {
            oA[r] = f2b(accO[0][t2][r] * linvA);
            oB[r] = f2b(accO[1][t2][r] * linvB);
        }
        *(u16x4*)&O[((size_t)(b * S_ + qiA) * H_ + h) * DK_ + 16 * t2 + 4 * g] = oA;
        *(u16x4*)&O[((size_t)(b * S_ + qiB) * H_ + h) * DK_ + 16 * t2 + 4 * g] = oB;
    }
}

// ---------------- output GEMM: 128x128 tile, BK=64, global_load_lds + XOR swizzle, f32 out ----------------
__launch_bounds__(256)
__global__ void gemm_out(const u16* __restrict__ Ob, const u16* __restrict__ WoT,
                         const float* __restrict__ bo, float* __restrict__ out) {
    __shared__ __attribute__((aligned(16))) u16 As[128][64];
    __shared__ __attribute__((aligned(16))) u16 Bs[128][64];

    const int tid = threadIdx.x;
    const int lane = tid & 63, w = tid >> 6;
    const int wr = w >> 1, wc = w & 1;
    const int g = lane >> 4, c = lane & 15;
    const int bm0 = blockIdx.y * 128, bn0 = blockIdx.x * 128;

    const int trow = tid >> 3;
    const int tcg = (tid & 7) ^ (trow & 7);
    const u16* gA = Ob + (size_t)(bm0 + trow) * D_ + 8 * tcg;
    const u16* gB = WoT + (size_t)(bn0 + trow) * D_ + 8 * tcg;

    f32x4 acc[4][4];
#pragma unroll
    for (int i = 0; i < 4; i++)
#pragma unroll
        for (int j = 0; j < 4; j++) acc[i][j] = (f32x4)0.0f;

    for (int k0 = 0; k0 < D_; k0 += 64) {
#pragma unroll
        for (int i = 0; i < 4; i++) {
            gload16(gA + (size_t)(32 * i) * D_ + k0, &As[0][0] + 512 * w + 2048 * i);
            gload16(gB + (size_t)(32 * i) * D_ + k0, &Bs[0][0] + 512 * w + 2048 * i);
        }
        __syncthreads();
#pragma unroll
        for (int kk = 0; kk < 2; kk++) {
            bf16x8 a[4], b[4];
#pragma unroll
            for (int mi = 0; mi < 4; mi++)
                a[mi] = *(const bf16x8*)&As[wr * 64 + 16 * mi + c][8 * ((4 * kk + g) ^ (c & 7))];
#pragma unroll
            for (int ni = 0; ni < 4; ni++)
                b[ni] = *(const bf16x8*)&Bs[wc * 64 + 16 * ni + c][8 * ((4 * kk + g) ^ (c & 7))];
#pragma unroll
            for (int mi = 0; mi < 4; mi++)
#pragma unroll
                for (int ni = 0; ni < 4; ni++)
                    acc[mi][ni] = __builtin_amdgcn_mfma_f32_16x16x32_bf16(a[mi], b[ni], acc[mi][ni], 0, 0, 0);
        }
        __syncthreads();
    }
#pragma unroll
    for (int mi = 0; mi < 4; mi++)
#pragma unroll
        for (int ni = 0; ni < 4; ni++)
#pragma unroll
            for (int r = 0; r < 4; r++) {
                int m = bm0 + wr * 64 + 16 * mi + 4 * g + r;
                int n = bn0 + wc * 64 + 16 * ni + c;
                out[(size_t)m * D_ + n] = acc[mi][ni][r] + bo[n];
            }
}

extern "C" void kernel_launch(void* const* d_in, const int* in_sizes, int n_in,
                              void* d_out, int out_size, void* d_ws, size_t ws_size,
                              hipStream_t stream) {
    const float* x  = (const float*)d_in[0];
    const float* Wq = (const float*)d_in[1];
    const float* bq = (const float*)d_in[2];
    const float* Wk = (const float*)d_in[3];
    const float* bk = (const float*)d_in[4];
    const float* Wv = (const float*)d_in[5];
    const float* bv = (const float*)d_in[6];
    const float* Wo = (const float*)d_in[7];
    const float* bo = (const float*)d_in[8];
    const int* mb   = (const int*)d_in[9];
    float* out = (float*)d_out;

    char* p = (char*)d_ws;
    u16* wt = (u16*)p; p += (size_t)4 * D_ * D_ * 2;
    u16* qw = (u16*)p; p += (size_t)MS_ * D_ * 2;
    u16* kw = (u16*)p; p += (size_t)MS_ * D_ * 2;
    u16* vw = (u16*)p; p += (size_t)MS_ * D_ * 2;
    u16* ow = (u16*)p; p += (size_t)MS_ * D_ * 2;

    transpose_cast<<<dim3(16, 16, 4), 256, 0, stream>>>(Wq, Wk, Wv, Wo, wt);

    gemm_qkv<<<dim3(4, 64, 3), 256, 0, stream>>>(x, wt, bq, bk, bv, qw, kw, vw);
    attn_kernel<<<dim3(64, 8), 512, 0, stream>>>(qw, kw, vw, ow, mb);
    gemm_out<<<dim3(4, 64), 256, 0, stream>>>(ow, wt + (size_t)3 * D_ * D_, bo, out);
}

// Round 13
// 101.696 us; speedup vs baseline: 1.0623x; 1.0623x over previous
//
#include <hip/hip_runtime.h>
#include <hip/hip_bf16.h>

#define B_ 4
#define S_ 2048
#define D_ 512
#define H_ 16
#define DK_ 32
#define MS_ 8192   // B_*S_

typedef unsigned short u16;
typedef __attribute__((ext_vector_type(4))) unsigned short u16x4;
typedef __attribute__((ext_vector_type(8))) short bf16x8;
typedef __attribute__((ext_vector_type(4))) float f32x4;

union pbu { unsigned u[4]; bf16x8 v; };

__device__ __forceinline__ u16 f2b(float f) {
    union { float f; unsigned u; } uf; uf.f = f;
    unsigned u = uf.u;
    unsigned r = u + 0x7fffu + ((u >> 16) & 1u);  // RNE
    return (u16)(r >> 16);
}

__device__ __forceinline__ unsigned cvt_pk_bf16(float lo, float hi) {
    unsigned r;
    asm("v_cvt_pk_bf16_f32 %0, %1, %2" : "=v"(r) : "v"(lo), "v"(hi));
    return r;
}

// async global->LDS, 16B per lane; dst is wave-uniform base, HW adds lane*16
__device__ __forceinline__ void gload16(const u16* src, u16* dst) {
    __builtin_amdgcn_global_load_lds(
        (const __attribute__((address_space(1))) unsigned int*)src,
        (__attribute__((address_space(3))) unsigned int*)dst, 16, 0, 0);
}

// ---------------- cast f32 -> bf16 (vectorized x4) ----------------
__global__ void cast_f32_to_bf16(const float* __restrict__ in, u16* __restrict__ out, int n4) {
    int i = blockIdx.x * blockDim.x + threadIdx.x;
    if (i >= n4) return;
    f32x4 v = *(const f32x4*)(in + (size_t)i * 4);
    u16x4 o;
    o[0] = f2b(v[0]); o[1] = f2b(v[1]); o[2] = f2b(v[2]); o[3] = f2b(v[3]);
    *(u16x4*)(out + (size_t)i * 4) = o;
}

// ---------------- transpose+cast 4 weight matrices: WT[z][n][k] = W_z[k][n] ----------------
__global__ void transpose_cast(const float* __restrict__ Wq, const float* __restrict__ Wk,
                               const float* __restrict__ Wv, const float* __restrict__ Wo,
                               u16* __restrict__ out) {
    const int z = blockIdx.z;
    const float* W = (z == 0) ? Wq : (z == 1) ? Wk : (z == 2) ? Wv : Wo;
    u16* O = out + (size_t)z * D_ * D_;
    __shared__ float T[32][33];
    const int n0 = blockIdx.x * 32, k0 = blockIdx.y * 32;
    const int tx = threadIdx.x & 31, ty = threadIdx.x >> 5;
#pragma unroll
    for (int i = 0; i < 4; i++) {
        int row = ty + 8 * i;
        T[tx][row] = W[(size_t)(k0 + row) * D_ + n0 + tx];
    }
    __syncthreads();
#pragma unroll
    for (int i = 0; i < 4; i++) {
        int row = ty + 8 * i;
        O[(size_t)(n0 + row) * D_ + k0 + tx] = f2b(T[row][tx]);
    }
}

// ---------------- QKV GEMM: 64x128 tile (M-split), BK=64, global_load_lds + XOR swizzle ----------------
// 1536 blocks (6/CU). Q output pre-scaled by log2(e)/sqrt(32).
__launch_bounds__(256)
__global__ void gemm_qkv(const u16* __restrict__ Xb, const u16* __restrict__ WT,
                         const float* __restrict__ bq, const float* __restrict__ bk, const float* __restrict__ bv,
                         u16* __restrict__ Qw, u16* __restrict__ Kw, u16* __restrict__ Vw) {
    const int which = blockIdx.z;
    const u16* Wt = WT + (size_t)which * D_ * D_;
    const float* bias = (which == 0) ? bq : (which == 1) ? bk : bv;
    u16* Out = (which == 0) ? Qw : (which == 1) ? Kw : Vw;
    const float oscale = (which == 0) ? (float)(1.4426950408889634 / 5.656854249492381) : 1.0f;

    __shared__ __attribute__((aligned(16))) u16 As[64][64];
    __shared__ __attribute__((aligned(16))) u16 Bs[128][64];

    const int tid = threadIdx.x;
    const int lane = tid & 63, w = tid >> 6;
    const int wr = w >> 1, wc = w & 1;     // 2x2 waves; each wave 32(M) x 64(N)
    const int g = lane >> 4, c = lane & 15;
    const int bm0 = blockIdx.y * 64, bn0 = blockIdx.x * 128;

    const int trow = tid >> 3;
    const int tcg = (tid & 7) ^ (trow & 7);
    const u16* gA = Xb + (size_t)(bm0 + trow) * D_ + 8 * tcg;
    const u16* gB = Wt + (size_t)(bn0 + trow) * D_ + 8 * tcg;

    f32x4 acc[2][4];
#pragma unroll
    for (int i = 0; i < 2; i++)
#pragma unroll
        for (int j = 0; j < 4; j++) acc[i][j] = (f32x4)0.0f;

    for (int k0 = 0; k0 < D_; k0 += 64) {
#pragma unroll
        for (int i = 0; i < 2; i++)
            gload16(gA + (size_t)(32 * i) * D_ + k0, &As[0][0] + 512 * w + 2048 * i);
#pragma unroll
        for (int i = 0; i < 4; i++)
            gload16(gB + (size_t)(32 * i) * D_ + k0, &Bs[0][0] + 512 * w + 2048 * i);
        __syncthreads();
#pragma unroll
        for (int kk = 0; kk < 2; kk++) {
            bf16x8 a[2], b[4];
#pragma unroll
            for (int mi = 0; mi < 2; mi++)
                a[mi] = *(const bf16x8*)&As[wr * 32 + 16 * mi + c][8 * ((4 * kk + g) ^ (c & 7))];
#pragma unroll
            for (int ni = 0; ni < 4; ni++)
                b[ni] = *(const bf16x8*)&Bs[wc * 64 + 16 * ni + c][8 * ((4 * kk + g) ^ (c & 7))];
#pragma unroll
            for (int mi = 0; mi < 2; mi++)
#pragma unroll
                for (int ni = 0; ni < 4; ni++)
                    acc[mi][ni] = __builtin_amdgcn_mfma_f32_16x16x32_bf16(a[mi], b[ni], acc[mi][ni], 0, 0, 0);
        }
        __syncthreads();
    }
#pragma unroll
    for (int mi = 0; mi < 2; mi++)
#pragma unroll
        for (int ni = 0; ni < 4; ni++)
#pragma unroll
            for (int r = 0; r < 4; r++) {
                int m = bm0 + wr * 32 + 16 * mi + 4 * g + r;
                int n = bn0 + wc * 64 + 16 * ni + c;
                float v = (acc[mi][ni][r] + bias[n]) * oscale;
                int b = m >> 11, s = m & 2047;
                int h = n >> 5, dk = n & 31;
                Out[(((size_t)(b * H_ + h) * S_) + s) * DK_ + dk] = f2b(v);
            }
}

// ---------------- flash attention (r11-exact: r7 body + setprio) ----------------
// 256 q per block (8 waves x 32 q), KVBLK=128 (two verified 64-kv subtiles),
// single buffer, 2 barriers/tile, Q pre-scaled (exp2 direct), row-sum via ones-MFMA.
__launch_bounds__(512)
__global__ void attn_kernel(const u16* __restrict__ Q, const u16* __restrict__ K,
                            const u16* __restrict__ V, u16* __restrict__ O,
                            const int* __restrict__ mbp) {
    const int border = *mbp;
    const unsigned b2u = (unsigned)(2 * border);
    const int bh = blockIdx.x;          // all q-blocks of one bh -> same XCD (ids differ by 64)
    const int q0 = blockIdx.y * 256;
    const int tid = threadIdx.x;
    const int lane = tid & 63;
    const int w = __builtin_amdgcn_readfirstlane(tid >> 6);   // wave-uniform
    const int g = lane >> 4, c = lane & 15;

    __shared__ __attribute__((aligned(16))) u16 Ks[128][32];     // two permuted 64-row halves
    __shared__ __attribute__((aligned(16))) u16 Vt[2][32][68];   // [kv-half][dv][kk]

    const u16* Qbh = Q + (size_t)bh * S_ * DK_;
    const u16* Kbh = K + (size_t)bh * S_ * DK_;
    const u16* Vbh = V + (size_t)bh * S_ * DK_;

    const int qw0 = q0 + w * 32;        // wave-uniform
    const int qiA = qw0 + c;
    const int qiB = qw0 + 16 + c;
    const bf16x8 qfA = *(const bf16x8*)&Qbh[(size_t)qiA * DK_ + 8 * g];
    const bf16x8 qfB = *(const bf16x8*)&Qbh[(size_t)qiB * DK_ + 8 * g];

    f32x4 accO[2][2];   // [qs][dv-half]
    f32x4 accL[2];      // [qs] row-sum accumulator (all rows identical)
#pragma unroll
    for (int i = 0; i < 2; i++) { accO[i][0] = (f32x4)0.0f; accO[i][1] = (f32x4)0.0f; accL[i] = (f32x4)0.0f; }

    const float C2 = 1.4426950408889634f;   // log2(e) * 1.0 (band add, post-scale)

    // ones A-fragment for row-sum MFMA (constant -> layout-independent)
    union { u16x4 h[2]; bf16x8 v; } ones;
#pragma unroll
    for (int j = 0; j < 4; j++) { ones.h[0][j] = 0x3F80; ones.h[1][j] = 0x3F80; }

    // staging indices (round-2 verified): 512 thr x u16x4 covers one 64x32 tile
    const int skk = tid >> 3;
    const int sc4 = (tid & 7) << 2;
    const int srow = 32 * ((skk >> 2) & 1) + 16 * ((skk >> 5) & 1) + (((skk >> 3) & 3) << 2) + (skk & 3);

    // softmax+pack for one 16-q subtile vs one 64-kv subtile
    auto sm_pack = [&](const f32x4* sf, int qs0, int qiv, int kvs, pbu* pb) {
        float e[4][4];
        const bool aOut = (qs0 > kvs + 63 + border) || (qs0 + 15 + border < kvs);
        const bool aIn  = (qs0 + 15 <= kvs + border) && (kvs + 63 <= qs0 + border);
        if (aOut) {
#pragma unroll
            for (int ct = 0; ct < 4; ct++)
#pragma unroll
                for (int r = 0; r < 4; r++)
                    e[ct][r] = __builtin_amdgcn_exp2f(sf[ct][r]);
        } else if (aIn) {
#pragma unroll
            for (int ct = 0; ct < 4; ct++)
#pragma unroll
                for (int r = 0; r < 4; r++)
                    e[ct][r] = __builtin_amdgcn_exp2f(sf[ct][r] + C2);
        } else {
            const int qb = qiv + border - kvs;
#pragma unroll
            for (int ct = 0; ct < 4; ct++) {
                const int k0l = 32 * (ct & 1) + 8 * g + 4 * (ct >> 1);
#pragma unroll
                for (int r = 0; r < 4; r++) {
                    float a = ((unsigned)(qb - (k0l + r)) <= b2u) ? C2 : 0.0f;
                    e[ct][r] = __builtin_amdgcn_exp2f(sf[ct][r] + a);
                }
            }
        }
        // pack (round-2 verified ordering)
        pb[0].u[0] = cvt_pk_bf16(e[0][0], e[0][1]);
        pb[0].u[1] = cvt_pk_bf16(e[0][2], e[0][3]);
        pb[0].u[2] = cvt_pk_bf16(e[2][0], e[2][1]);
        pb[0].u[3] = cvt_pk_bf16(e[2][2], e[2][3]);
        pb[1].u[0] = cvt_pk_bf16(e[1][0], e[1][1]);
        pb[1].u[1] = cvt_pk_bf16(e[1][2], e[1][3]);
        pb[1].u[2] = cvt_pk_bf16(e[3][0], e[3][1]);
        pb[1].u[3] = cvt_pk_bf16(e[3][2], e[3][3]);
    };

    // one 64-kv subtile: QK^T (both q-subtiles) -> softmax -> PV + row-sum MFMA
    auto do_sub = [&](int sub, int kvs) {
        f32x4 sA[4], sB[4];
#pragma unroll
        for (int ct = 0; ct < 4; ct++) {
            const bf16x8 kf = *(const bf16x8*)&Ks[sub * 64 + 16 * ct + c][8 * g];
            sA[ct] = __builtin_amdgcn_mfma_f32_16x16x32_bf16(kf, qfA, (f32x4)0.0f, 0, 0, 0);
            sB[ct] = __builtin_amdgcn_mfma_f32_16x16x32_bf16(kf, qfB, (f32x4)0.0f, 0, 0, 0);
        }
        pbu pA[2], pB[2];
        sm_pack(sA, qw0, qiA, kvs, pA);
        sm_pack(sB, qw0 + 16, qiB, kvs, pB);
#pragma unroll
        for (int t2 = 0; t2 < 2; t2++) {
#pragma unroll
            for (int ksl = 0; ksl < 2; ksl++) {
                union { u16x4 h[2]; bf16x8 v; } vf;
                vf.h[0] = *(const u16x4*)&Vt[sub][16 * t2 + c][32 * ksl + 8 * g];
                vf.h[1] = *(const u16x4*)&Vt[sub][16 * t2 + c][32 * ksl + 8 * g + 4];
                accO[0][t2] = __builtin_amdgcn_mfma_f32_16x16x32_bf16(vf.v, pA[ksl].v, accO[0][t2], 0, 0, 0);
                accO[1][t2] = __builtin_amdgcn_mfma_f32_16x16x32_bf16(vf.v, pB[ksl].v, accO[1][t2], 0, 0, 0);
            }
        }
#pragma unroll
        for (int ksl = 0; ksl < 2; ksl++) {
            accL[0] = __builtin_amdgcn_mfma_f32_16x16x32_bf16(ones.v, pA[ksl].v, accL[0], 0, 0, 0);
            accL[1] = __builtin_amdgcn_mfma_f32_16x16x32_bf16(ones.v, pB[ksl].v, accL[1], 0, 0, 0);
        }
    };

    for (int kv0 = 0; kv0 < S_; kv0 += 128) {
        // stage both K halves (permuted rows) + both V^T halves (r7-verified, single buffer)
        *(u16x4*)&Ks[srow][sc4]      = *(const u16x4*)&Kbh[(size_t)(kv0 + skk) * DK_ + sc4];
        *(u16x4*)&Ks[64 + srow][sc4] = *(const u16x4*)&Kbh[(size_t)(kv0 + 64 + skk) * DK_ + sc4];
        u16x4 va = *(const u16x4*)&Vbh[(size_t)(kv0 + skk) * DK_ + sc4];
        u16x4 vb = *(const u16x4*)&Vbh[(size_t)(kv0 + 64 + skk) * DK_ + sc4];
#pragma unroll
        for (int j = 0; j < 4; j++) {
            Vt[0][sc4 + j][skk] = va[j];
            Vt[1][sc4 + j][skk] = vb[j];
        }
        __syncthreads();

        __builtin_amdgcn_s_setprio(1);
        do_sub(0, kv0);
        do_sub(1, kv0 + 64);
        __builtin_amdgcn_s_setprio(0);

        __syncthreads();
    }

    // epilogue: l from accL (all rows equal; col c corresponds to this lane's q)
    const int b = bh >> 4, h = bh & 15;
    const float linvA = 1.0f / accL[0][0];
    const float linvB = 1.0f / accL[1][0];
#pragma unroll
    for (int t2 = 0; t2 < 2; t2++) {
        u16x4 oA, oB;
#pragma unroll
        for (int r = 0; r < 4; r++) {
            oA[r] = f2b(accO[0][t2][r] * linvA);
            oB[r] = f2b(accO[1][t2][r] * linvB);
        }
        *(u16x4*)&O[((size_t)(b * S_ + qiA) * H_ + h) * DK_ + 16 * t2 + 4 * g] = oA;
        *(u16x4*)&O[((size_t)(b * S_ + qiB) * H_ + h) * DK_ + 16 * t2 + 4 * g] = oB;
    }
}

// ---------------- output GEMM: 64x128 tile (M-split), BK=64, 512 blocks (2/CU), f32 out ----------------
__launch_bounds__(256)
__global__ void gemm_out(const u16* __restrict__ Ob, const u16* __restrict__ WoT,
                         const float* __restrict__ bo, float* __restrict__ out) {
    __shared__ __attribute__((aligned(16))) u16 As[64][64];
    __shared__ __attribute__((aligned(16))) u16 Bs[128][64];

    const int tid = threadIdx.x;
    const int lane = tid & 63, w = tid >> 6;
    const int wr = w >> 1, wc = w & 1;     // 2x2 waves; each wave 32(M) x 64(N)
    const int g = lane >> 4, c = lane & 15;
    const int bm0 = blockIdx.y * 64, bn0 = blockIdx.x * 128;

    const int trow = tid >> 3;
    const int tcg = (tid & 7) ^ (trow & 7);
    const u16* gA = Ob + (size_t)(bm0 + trow) * D_ + 8 * tcg;
    const u16* gB = WoT + (size_t)(bn0 + trow) * D_ + 8 * tcg;

    f32x4 acc[2][4];
#pragma unroll
    for (int i = 0; i < 2; i++)
#pragma unroll
        for (int j = 0; j < 4; j++) acc[i][j] = (f32x4)0.0f;

    for (int k0 = 0; k0 < D_; k0 += 64) {
#pragma unroll
        for (int i = 0; i < 2; i++)
            gload16(gA + (size_t)(32 * i) * D_ + k0, &As[0][0] + 512 * w + 2048 * i);
#pragma unroll
        for (int i = 0; i < 4; i++)
            gload16(gB + (size_t)(32 * i) * D_ + k0, &Bs[0][0] + 512 * w + 2048 * i);
        __syncthreads();
#pragma unroll
        for (int kk = 0; kk < 2; kk++) {
            bf16x8 a[2], b[4];
#pragma unroll
            for (int mi = 0; mi < 2; mi++)
                a[mi] = *(const bf16x8*)&As[wr * 32 + 16 * mi + c][8 * ((4 * kk + g) ^ (c & 7))];
#pragma unroll
            for (int ni = 0; ni < 4; ni++)
                b[ni] = *(const bf16x8*)&Bs[wc * 64 + 16 * ni + c][8 * ((4 * kk + g) ^ (c & 7))];
#pragma unroll
            for (int mi = 0; mi < 2; mi++)
#pragma unroll
                for (int ni = 0; ni < 4; ni++)
                    acc[mi][ni] = __builtin_amdgcn_mfma_f32_16x16x32_bf16(a[mi], b[ni], acc[mi][ni], 0, 0, 0);
        }
        __syncthreads();
    }
#pragma unroll
    for (int mi = 0; mi < 2; mi++)
#pragma unroll
        for (int ni = 0; ni < 4; ni++)
#pragma unroll
            for (int r = 0; r < 4; r++) {
                int m = bm0 + wr * 32 + 16 * mi + 4 * g + r;
                int n = bn0 + wc * 64 + 16 * ni + c;
                out[(size_t)m * D_ + n] = acc[mi][ni][r] + bo[n];
            }
}

extern "C" void kernel_launch(void* const* d_in, const int* in_sizes, int n_in,
                              void* d_out, int out_size, void* d_ws, size_t ws_size,
                              hipStream_t stream) {
    const float* x  = (const float*)d_in[0];
    const float* Wq = (const float*)d_in[1];
    const float* bq = (const float*)d_in[2];
    const float* Wk = (const float*)d_in[3];
    const float* bk = (const float*)d_in[4];
    const float* Wv = (const float*)d_in[5];
    const float* bv = (const float*)d_in[6];
    const float* Wo = (const float*)d_in[7];
    const float* bo = (const float*)d_in[8];
    const int* mb   = (const int*)d_in[9];
    float* out = (float*)d_out;

    char* p = (char*)d_ws;
    u16* xb = (u16*)p; p += (size_t)MS_ * D_ * 2;
    u16* wt = (u16*)p; p += (size_t)4 * D_ * D_ * 2;
    u16* qw = (u16*)p; p += (size_t)MS_ * D_ * 2;
    u16* kw = (u16*)p; p += (size_t)MS_ * D_ * 2;
    u16* vw = (u16*)p; p += (size_t)MS_ * D_ * 2;
    u16* ow = (u16*)p; p += (size_t)MS_ * D_ * 2;

    cast_f32_to_bf16<<<4096, 256, 0, stream>>>(x, xb, MS_ * D_ / 4);
    transpose_cast<<<dim3(16, 16, 4), 256, 0, stream>>>(Wq, Wk, Wv, Wo, wt);

    gemm_qkv<<<dim3(4, 128, 3), 256, 0, stream>>>(xb, wt, bq, bk, bv, qw, kw, vw);
    attn_kernel<<<dim3(64, 8), 512, 0, stream>>>(qw, kw, vw, ow, mb);
    gemm_out<<<dim3(4, 128), 256, 0, stream>>>(ow, wt + (size_t)3 * D_ * D_, bo, out);
}

// Round 14
// 99.325 us; speedup vs baseline: 1.0876x; 1.0239x over previous
//
#include <hip/hip_runtime.h>
#include <hip/hip_bf16.h>

#define B_ 4
#define S_ 2048
#define D_ 512
#define H_ 16
#define DK_ 32
#define MS_ 8192   // B_*S_

typedef unsigned short u16;
typedef __attribute__((ext_vector_type(4))) unsigned short u16x4;
typedef __attribute__((ext_vector_type(8))) short bf16x8;
typedef __attribute__((ext_vector_type(4))) float f32x4;

union pbu { unsigned u[4]; bf16x8 v; };

__device__ __forceinline__ u16 f2b(float f) {
    union { float f; unsigned u; } uf; uf.f = f;
    unsigned u = uf.u;
    unsigned r = u + 0x7fffu + ((u >> 16) & 1u);  // RNE
    return (u16)(r >> 16);
}

__device__ __forceinline__ unsigned cvt_pk_bf16(float lo, float hi) {
    unsigned r;
    asm("v_cvt_pk_bf16_f32 %0, %1, %2" : "=v"(r) : "v"(lo), "v"(hi));
    return r;
}

// async global->LDS, 16B per lane; dst is wave-uniform base, HW adds lane*16
__device__ __forceinline__ void gload16(const u16* src, u16* dst) {
    __builtin_amdgcn_global_load_lds(
        (const __attribute__((address_space(1))) unsigned int*)src,
        (__attribute__((address_space(3))) unsigned int*)dst, 16, 0, 0);
}

// ---------------- cast f32 -> bf16 (vectorized x4) ----------------
__global__ void cast_f32_to_bf16(const float* __restrict__ in, u16* __restrict__ out, int n4) {
    int i = blockIdx.x * blockDim.x + threadIdx.x;
    if (i >= n4) return;
    f32x4 v = *(const f32x4*)(in + (size_t)i * 4);
    u16x4 o;
    o[0] = f2b(v[0]); o[1] = f2b(v[1]); o[2] = f2b(v[2]); o[3] = f2b(v[3]);
    *(u16x4*)(out + (size_t)i * 4) = o;
}

// ---------------- transpose+cast 4 weight matrices: WT[z][n][k] = W_z[k][n] ----------------
__global__ void transpose_cast(const float* __restrict__ Wq, const float* __restrict__ Wk,
                               const float* __restrict__ Wv, const float* __restrict__ Wo,
                               u16* __restrict__ out) {
    const int z = blockIdx.z;
    const float* W = (z == 0) ? Wq : (z == 1) ? Wk : (z == 2) ? Wv : Wo;
    u16* O = out + (size_t)z * D_ * D_;
    __shared__ float T[32][33];
    const int n0 = blockIdx.x * 32, k0 = blockIdx.y * 32;
    const int tx = threadIdx.x & 31, ty = threadIdx.x >> 5;
#pragma unroll
    for (int i = 0; i < 4; i++) {
        int row = ty + 8 * i;
        T[tx][row] = W[(size_t)(k0 + row) * D_ + n0 + tx];
    }
    __syncthreads();
#pragma unroll
    for (int i = 0; i < 4; i++) {
        int row = ty + 8 * i;
        O[(size_t)(n0 + row) * D_ + k0 + tx] = f2b(T[row][tx]);
    }
}

// ---------------- QKV GEMM: 128x128 tile, BK=64, global_load_lds + XOR swizzle ----------------
// Q output pre-scaled by log2(e)/sqrt(32) so attn exp2 consumes scores directly.
__launch_bounds__(256)
__global__ void gemm_qkv(const u16* __restrict__ Xb, const u16* __restrict__ WT,
                         const float* __restrict__ bq, const float* __restrict__ bk, const float* __restrict__ bv,
                         u16* __restrict__ Qw, u16* __restrict__ Kw, u16* __restrict__ Vw) {
    const int which = blockIdx.z;
    const u16* Wt = WT + (size_t)which * D_ * D_;
    const float* bias = (which == 0) ? bq : (which == 1) ? bk : bv;
    u16* Out = (which == 0) ? Qw : (which == 1) ? Kw : Vw;
    const float oscale = (which == 0) ? (float)(1.4426950408889634 / 5.656854249492381) : 1.0f;

    __shared__ __attribute__((aligned(16))) u16 As[128][64];
    __shared__ __attribute__((aligned(16))) u16 Bs[128][64];

    const int tid = threadIdx.x;
    const int lane = tid & 63, w = tid >> 6;
    const int wr = w >> 1, wc = w & 1;
    const int g = lane >> 4, c = lane & 15;
    const int bm0 = blockIdx.y * 128, bn0 = blockIdx.x * 128;

    const int trow = tid >> 3;
    const int tcg = (tid & 7) ^ (trow & 7);
    const u16* gA = Xb + (size_t)(bm0 + trow) * D_ + 8 * tcg;
    const u16* gB = Wt + (size_t)(bn0 + trow) * D_ + 8 * tcg;

    f32x4 acc[4][4];
#pragma unroll
    for (int i = 0; i < 4; i++)
#pragma unroll
        for (int j = 0; j < 4; j++) acc[i][j] = (f32x4)0.0f;

    for (int k0 = 0; k0 < D_; k0 += 64) {
#pragma unroll
        for (int i = 0; i < 4; i++) {
            gload16(gA + (size_t)(32 * i) * D_ + k0, &As[0][0] + 512 * w + 2048 * i);
            gload16(gB + (size_t)(32 * i) * D_ + k0, &Bs[0][0] + 512 * w + 2048 * i);
        }
        __syncthreads();
#pragma unroll
        for (int kk = 0; kk < 2; kk++) {
            bf16x8 a[4], b[4];
#pragma unroll
            for (int mi = 0; mi < 4; mi++)
                a[mi] = *(const bf16x8*)&As[wr * 64 + 16 * mi + c][8 * ((4 * kk + g) ^ (c & 7))];
#pragma unroll
            for (int ni = 0; ni < 4; ni++)
                b[ni] = *(const bf16x8*)&Bs[wc * 64 + 16 * ni + c][8 * ((4 * kk + g) ^ (c & 7))];
#pragma unroll
            for (int mi = 0; mi < 4; mi++)
#pragma unroll
                for (int ni = 0; ni < 4; ni++)
                    acc[mi][ni] = __builtin_amdgcn_mfma_f32_16x16x32_bf16(a[mi], b[ni], acc[mi][ni], 0, 0, 0);
        }
        __syncthreads();
    }
#pragma unroll
    for (int mi = 0; mi < 4; mi++)
#pragma unroll
        for (int ni = 0; ni < 4; ni++)
#pragma unroll
            for (int r = 0; r < 4; r++) {
                int m = bm0 + wr * 64 + 16 * mi + 4 * g + r;
                int n = bn0 + wc * 64 + 16 * ni + c;
                float v = (acc[mi][ni][r] + bias[n]) * oscale;
                int b = m >> 11, s = m & 2047;
                int h = n >> 5, dk = n & 31;
                Out[(((size_t)(b * H_ + h) * S_) + s) * DK_ + dk] = f2b(v);
            }
}

// ---------------- flash attention (r11 body; K staged via gload16 w/ correct inverse perm) ----------------
// 256 q per block (8 waves x 32 q), KVBLK=128, single buffer, 2 barriers/tile,
// Q pre-scaled (exp2 direct), row-sum via ones-MFMA, setprio around compute.
__launch_bounds__(512)
__global__ void attn_kernel(const u16* __restrict__ Q, const u16* __restrict__ K,
                            const u16* __restrict__ V, u16* __restrict__ O,
                            const int* __restrict__ mbp) {
    const int border = *mbp;
    const unsigned b2u = (unsigned)(2 * border);
    const int bh = blockIdx.x;          // all q-blocks of one bh -> same XCD (ids differ by 64)
    const int q0 = blockIdx.y * 256;
    const int tid = threadIdx.x;
    const int lane = tid & 63;
    const int w = __builtin_amdgcn_readfirstlane(tid >> 6);   // wave-uniform
    const int g = lane >> 4, c = lane & 15;

    __shared__ __attribute__((aligned(16))) u16 Ks[128][32];     // two permuted 64-row halves
    __shared__ __attribute__((aligned(16))) u16 Vt[2][32][68];   // [kv-half][dv][kk]

    const u16* Qbh = Q + (size_t)bh * S_ * DK_;
    const u16* Kbh = K + (size_t)bh * S_ * DK_;
    const u16* Vbh = V + (size_t)bh * S_ * DK_;

    const int qw0 = q0 + w * 32;        // wave-uniform
    const int qiA = qw0 + c;
    const int qiB = qw0 + 16 + c;
    const bf16x8 qfA = *(const bf16x8*)&Qbh[(size_t)qiA * DK_ + 8 * g];
    const bf16x8 qfB = *(const bf16x8*)&Qbh[(size_t)qiB * DK_ + 8 * g];

    f32x4 accO[2][2];   // [qs][dv-half]
    f32x4 accL[2];      // [qs] row-sum accumulator (all rows identical)
#pragma unroll
    for (int i = 0; i < 2; i++) { accO[i][0] = (f32x4)0.0f; accO[i][1] = (f32x4)0.0f; accL[i] = (f32x4)0.0f; }

    const float C2 = 1.4426950408889634f;   // log2(e) * 1.0 (band add, post-scale)

    // ones A-fragment for row-sum MFMA (constant -> layout-independent)
    union { u16x4 h[2]; bf16x8 v; } ones;
#pragma unroll
    for (int j = 0; j < 4; j++) { ones.h[0][j] = 0x3F80; ones.h[1][j] = 0x3F80; }

    // K staging via gload16: lane fills LDS row L = 16w + (lane>>2), granule lane&3.
    // Global row = inverse of verified forward map srow(skk)=32*b2+16*b5+4*b34+b01:
    //   inv(L) = (L&3) + 4*((L>>5)&1) + 8*((L>>2)&3) + 32*((L>>4)&1); bit6 (half select) passes through.
    const int gl_L = 16 * w + (lane >> 2);
    const int gl_gr = (gl_L & 64) + (gl_L & 3) + 4 * ((gl_L >> 5) & 1)
                    + 8 * ((gl_L >> 2) & 3) + 32 * ((gl_L >> 4) & 1);
    const u16* ksrc = Kbh + (size_t)gl_gr * DK_ + 8 * (lane & 3);
    u16* kdst = &Ks[0][0] + (w << 9);   // wave-uniform base, w*1024 bytes

    // V staging indices (round-2 verified): 512 thr x u16x4 covers one 64x32 tile
    const int skk = tid >> 3;
    const int sc4 = (tid & 7) << 2;

    // softmax+pack for one 16-q subtile vs one 64-kv subtile
    auto sm_pack = [&](const f32x4* sf, int qs0, int qiv, int kvs, pbu* pb) {
        float e[4][4];
        const bool aOut = (qs0 > kvs + 63 + border) || (qs0 + 15 + border < kvs);
        const bool aIn  = (qs0 + 15 <= kvs + border) && (kvs + 63 <= qs0 + border);
        if (aOut) {
#pragma unroll
            for (int ct = 0; ct < 4; ct++)
#pragma unroll
                for (int r = 0; r < 4; r++)
                    e[ct][r] = __builtin_amdgcn_exp2f(sf[ct][r]);
        } else if (aIn) {
#pragma unroll
            for (int ct = 0; ct < 4; ct++)
#pragma unroll
                for (int r = 0; r < 4; r++)
                    e[ct][r] = __builtin_amdgcn_exp2f(sf[ct][r] + C2);
        } else {
            const int qb = qiv + border - kvs;
#pragma unroll
            for (int ct = 0; ct < 4; ct++) {
                const int k0l = 32 * (ct & 1) + 8 * g + 4 * (ct >> 1);
#pragma unroll
                for (int r = 0; r < 4; r++) {
                    float a = ((unsigned)(qb - (k0l + r)) <= b2u) ? C2 : 0.0f;
                    e[ct][r] = __builtin_amdgcn_exp2f(sf[ct][r] + a);
                }
            }
        }
        // pack (round-2 verified ordering)
        pb[0].u[0] = cvt_pk_bf16(e[0][0], e[0][1]);
        pb[0].u[1] = cvt_pk_bf16(e[0][2], e[0][3]);
        pb[0].u[2] = cvt_pk_bf16(e[2][0], e[2][1]);
        pb[0].u[3] = cvt_pk_bf16(e[2][2], e[2][3]);
        pb[1].u[0] = cvt_pk_bf16(e[1][0], e[1][1]);
        pb[1].u[1] = cvt_pk_bf16(e[1][2], e[1][3]);
        pb[1].u[2] = cvt_pk_bf16(e[3][0], e[3][1]);
        pb[1].u[3] = cvt_pk_bf16(e[3][2], e[3][3]);
    };

    // one 64-kv subtile: QK^T (both q-subtiles) -> softmax -> PV + row-sum MFMA
    auto do_sub = [&](int sub, int kvs) {
        f32x4 sA[4], sB[4];
#pragma unroll
        for (int ct = 0; ct < 4; ct++) {
            const bf16x8 kf = *(const bf16x8*)&Ks[sub * 64 + 16 * ct + c][8 * g];
            sA[ct] = __builtin_amdgcn_mfma_f32_16x16x32_bf16(kf, qfA, (f32x4)0.0f, 0, 0, 0);
            sB[ct] = __builtin_amdgcn_mfma_f32_16x16x32_bf16(kf, qfB, (f32x4)0.0f, 0, 0, 0);
        }
        pbu pA[2], pB[2];
        sm_pack(sA, qw0, qiA, kvs, pA);
        sm_pack(sB, qw0 + 16, qiB, kvs, pB);
#pragma unroll
        for (int t2 = 0; t2 < 2; t2++) {
#pragma unroll
            for (int ksl = 0; ksl < 2; ksl++) {
                union { u16x4 h[2]; bf16x8 v; } vf;
                vf.h[0] = *(const u16x4*)&Vt[sub][16 * t2 + c][32 * ksl + 8 * g];
                vf.h[1] = *(const u16x4*)&Vt[sub][16 * t2 + c][32 * ksl + 8 * g + 4];
                accO[0][t2] = __builtin_amdgcn_mfma_f32_16x16x32_bf16(vf.v, pA[ksl].v, accO[0][t2], 0, 0, 0);
                accO[1][t2] = __builtin_amdgcn_mfma_f32_16x16x32_bf16(vf.v, pB[ksl].v, accO[1][t2], 0, 0, 0);
            }
        }
#pragma unroll
        for (int ksl = 0; ksl < 2; ksl++) {
            accL[0] = __builtin_amdgcn_mfma_f32_16x16x32_bf16(ones.v, pA[ksl].v, accL[0], 0, 0, 0);
            accL[1] = __builtin_amdgcn_mfma_f32_16x16x32_bf16(ones.v, pB[ksl].v, accL[1], 0, 0, 0);
        }
    };

    for (int kv0 = 0; kv0 < S_; kv0 += 128) {
        // stage K (async DMA, permuted source rows) + both V^T halves (reg-staged, verified)
        gload16(ksrc + (size_t)kv0 * DK_, kdst);
        u16x4 va = *(const u16x4*)&Vbh[(size_t)(kv0 + skk) * DK_ + sc4];
        u16x4 vb = *(const u16x4*)&Vbh[(size_t)(kv0 + 64 + skk) * DK_ + sc4];
#pragma unroll
        for (int j = 0; j < 4; j++) {
            Vt[0][sc4 + j][skk] = va[j];
            Vt[1][sc4 + j][skk] = vb[j];
        }
        __syncthreads();   // drains vmcnt (K gload) + lgkm (V writes)

        __builtin_amdgcn_s_setprio(1);
        do_sub(0, kv0);
        do_sub(1, kv0 + 64);
        __builtin_amdgcn_s_setprio(0);

        __syncthreads();
    }

    // epilogue: l from accL (all rows equal; col c corresponds to this lane's q)
    const int b = bh >> 4, h = bh & 15;
    const float linvA = 1.0f / accL[0][0];
    const float linvB = 1.0f / accL[1][0];
#pragma unroll
    for (int t2 = 0; t2 < 2; t2++) {
        u16x4 oA, oB;
#pragma unroll
        for (int r = 0; r < 4; r++) {
            oA[r] = f2b(accO[0][t2][r] * linvA);
            oB[r] = f2b(accO[1][t2][r] * linvB);
        }
        *(u16x4*)&O[((size_t)(b * S_ + qiA) * H_ + h) * DK_ + 16 * t2 + 4 * g] = oA;
        *(u16x4*)&O[((size_t)(b * S_ + qiB) * H_ + h) * DK_ + 16 * t2 + 4 * g] = oB;
    }
}

// ---------------- output GEMM: 128x128 tile, BK=64, global_load_lds + XOR swizzle, f32 out ----------------
__launch_bounds__(256)
__global__ void gemm_out(const u16* __restrict__ Ob, const u16* __restrict__ WoT,
                         const float* __restrict__ bo, float* __restrict__ out) {
    __shared__ __attribute__((aligned(16))) u16 As[128][64];
    __shared__ __attribute__((aligned(16))) u16 Bs[128][64];

    const int tid = threadIdx.x;
    const int lane = tid & 63, w = tid >> 6;
    const int wr = w >> 1, wc = w & 1;
    const int g = lane >> 4, c = lane & 15;
    const int bm0 = blockIdx.y * 128, bn0 = blockIdx.x * 128;

    const int trow = tid >> 3;
    const int tcg = (tid & 7) ^ (trow & 7);
    const u16* gA = Ob + (size_t)(bm0 + trow) * D_ + 8 * tcg;
    const u16* gB = WoT + (size_t)(bn0 + trow) * D_ + 8 * tcg;

    f32x4 acc[4][4];
#pragma unroll
    for (int i = 0; i < 4; i++)
#pragma unroll
        for (int j = 0; j < 4; j++) acc[i][j] = (f32x4)0.0f;

    for (int k0 = 0; k0 < D_; k0 += 64) {
#pragma unroll
        for (int i = 0; i < 4; i++) {
            gload16(gA + (size_t)(32 * i) * D_ + k0, &As[0][0] + 512 * w + 2048 * i);
            gload16(gB + (size_t)(32 * i) * D_ + k0, &Bs[0][0] + 512 * w + 2048 * i);
        }
        __syncthreads();
#pragma unroll
        for (int kk = 0; kk < 2; kk++) {
            bf16x8 a[4], b[4];
#pragma unroll
            for (int mi = 0; mi < 4; mi++)
                a[mi] = *(const bf16x8*)&As[wr * 64 + 16 * mi + c][8 * ((4 * kk + g) ^ (c & 7))];
#pragma unroll
            for (int ni = 0; ni < 4; ni++)
                b[ni] = *(const bf16x8*)&Bs[wc * 64 + 16 * ni + c][8 * ((4 * kk + g) ^ (c & 7))];
#pragma unroll
            for (int mi = 0; mi < 4; mi++)
#pragma unroll
                for (int ni = 0; ni < 4; ni++)
                    acc[mi][ni] = __builtin_amdgcn_mfma_f32_16x16x32_bf16(a[mi], b[ni], acc[mi][ni], 0, 0, 0);
        }
        __syncthreads();
    }
#pragma unroll
    for (int mi = 0; mi < 4; mi++)
#pragma unroll
        for (int ni = 0; ni < 4; ni++)
#pragma unroll
            for (int r = 0; r < 4; r++) {
                int m = bm0 + wr * 64 + 16 * mi + 4 * g + r;
                int n = bn0 + wc * 64 + 16 * ni + c;
                out[(size_t)m * D_ + n] = acc[mi][ni][r] + bo[n];
            }
}

extern "C" void kernel_launch(void* const* d_in, const int* in_sizes, int n_in,
                              void* d_out, int out_size, void* d_ws, size_t ws_size,
                              hipStream_t stream) {
    const float* x  = (const float*)d_in[0];
    const float* Wq = (const float*)d_in[1];
    const float* bq = (const float*)d_in[2];
    const float* Wk = (const float*)d_in[3];
    const float* bk = (const float*)d_in[4];
    const float* Wv = (const float*)d_in[5];
    const float* bv = (const float*)d_in[6];
    const float* Wo = (const float*)d_in[7];
    const float* bo = (const float*)d_in[8];
    const int* mb   = (const int*)d_in[9];
    float* out = (float*)d_out;

    char* p = (char*)d_ws;
    u16* xb = (u16*)p; p += (size_t)MS_ * D_ * 2;
    u16* wt = (u16*)p; p += (size_t)4 * D_ * D_ * 2;
    u16* qw = (u16*)p; p += (size_t)MS_ * D_ * 2;
    u16* kw = (u16*)p; p += (size_t)MS_ * D_ * 2;
    u16* vw = (u16*)p; p += (size_t)MS_ * D_ * 2;
    u16* ow = (u16*)p; p += (size_t)MS_ * D_ * 2;

    cast_f32_to_bf16<<<4096, 256, 0, stream>>>(x, xb, MS_ * D_ / 4);
    transpose_cast<<<dim3(16, 16, 4), 256, 0, stream>>>(Wq, Wk, Wv, Wo, wt);

    gemm_qkv<<<dim3(4, 64, 3), 256, 0, stream>>>(xb, wt, bq, bk, bv, qw, kw, vw);
    attn_kernel<<<dim3(64, 8), 512, 0, stream>>>(qw, kw, vw, ow, mb);
    gemm_out<<<dim3(4, 64), 256, 0, stream>>>(ow, wt + (size_t)3 * D_ * D_, bo, out);
}

// Round 15
// 99.313 us; speedup vs baseline: 1.0878x; 1.0001x over previous
//
#include <hip/hip_runtime.h>
#include <hip/hip_bf16.h>

#define B_ 4
#define S_ 2048
#define D_ 512
#define H_ 16
#define DK_ 32
#define MS_ 8192   // B_*S_

typedef unsigned short u16;
typedef __attribute__((ext_vector_type(4))) unsigned short u16x4;
typedef __attribute__((ext_vector_type(8))) short bf16x8;
typedef __attribute__((ext_vector_type(4))) float f32x4;

union pbu { unsigned u[4]; bf16x8 v; };

__device__ __forceinline__ u16 f2b(float f) {
    union { float f; unsigned u; } uf; uf.f = f;
    unsigned u = uf.u;
    unsigned r = u + 0x7fffu + ((u >> 16) & 1u);  // RNE
    return (u16)(r >> 16);
}

__device__ __forceinline__ unsigned cvt_pk_bf16(float lo, float hi) {
    unsigned r;
    asm("v_cvt_pk_bf16_f32 %0, %1, %2" : "=v"(r) : "v"(lo), "v"(hi));
    return r;
}

// async global->LDS, 16B per lane; dst is wave-uniform base, HW adds lane*16
__device__ __forceinline__ void gload16(const u16* src, u16* dst) {
    __builtin_amdgcn_global_load_lds(
        (const __attribute__((address_space(1))) unsigned int*)src,
        (__attribute__((address_space(3))) unsigned int*)dst, 16, 0, 0);
}

// ---------------- cast f32 -> bf16 (vectorized x4) ----------------
__global__ void cast_f32_to_bf16(const float* __restrict__ in, u16* __restrict__ out, int n4) {
    int i = blockIdx.x * blockDim.x + threadIdx.x;
    if (i >= n4) return;
    f32x4 v = *(const f32x4*)(in + (size_t)i * 4);
    u16x4 o;
    o[0] = f2b(v[0]); o[1] = f2b(v[1]); o[2] = f2b(v[2]); o[3] = f2b(v[3]);
    *(u16x4*)(out + (size_t)i * 4) = o;
}

// ---------------- transpose+cast 4 weight matrices: WT[z][n][k] = W_z[k][n] ----------------
__global__ void transpose_cast(const float* __restrict__ Wq, const float* __restrict__ Wk,
                               const float* __restrict__ Wv, const float* __restrict__ Wo,
                               u16* __restrict__ out) {
    const int z = blockIdx.z;
    const float* W = (z == 0) ? Wq : (z == 1) ? Wk : (z == 2) ? Wv : Wo;
    u16* O = out + (size_t)z * D_ * D_;
    __shared__ float T[32][33];
    const int n0 = blockIdx.x * 32, k0 = blockIdx.y * 32;
    const int tx = threadIdx.x & 31, ty = threadIdx.x >> 5;
#pragma unroll
    for (int i = 0; i < 4; i++) {
        int row = ty + 8 * i;
        T[tx][row] = W[(size_t)(k0 + row) * D_ + n0 + tx];
    }
    __syncthreads();
#pragma unroll
    for (int i = 0; i < 4; i++) {
        int row = ty + 8 * i;
        O[(size_t)(n0 + row) * D_ + k0 + tx] = f2b(T[row][tx]);
    }
}

// ---------------- QKV GEMM: 128x128 tile, BK=64, global_load_lds + XOR swizzle ----------------
// Q output pre-scaled by log2(e)/sqrt(32) so attn exp2 consumes scores directly.
__launch_bounds__(256)
__global__ void gemm_qkv(const u16* __restrict__ Xb, const u16* __restrict__ WT,
                         const float* __restrict__ bq, const float* __restrict__ bk, const float* __restrict__ bv,
                         u16* __restrict__ Qw, u16* __restrict__ Kw, u16* __restrict__ Vw) {
    const int which = blockIdx.z;
    const u16* Wt = WT + (size_t)which * D_ * D_;
    const float* bias = (which == 0) ? bq : (which == 1) ? bk : bv;
    u16* Out = (which == 0) ? Qw : (which == 1) ? Kw : Vw;
    const float oscale = (which == 0) ? (float)(1.4426950408889634 / 5.656854249492381) : 1.0f;

    __shared__ __attribute__((aligned(16))) u16 As[128][64];
    __shared__ __attribute__((aligned(16))) u16 Bs[128][64];

    const int tid = threadIdx.x;
    const int lane = tid & 63, w = tid >> 6;
    const int wr = w >> 1, wc = w & 1;
    const int g = lane >> 4, c = lane & 15;
    const int bm0 = blockIdx.y * 128, bn0 = blockIdx.x * 128;

    const int trow = tid >> 3;
    const int tcg = (tid & 7) ^ (trow & 7);
    const u16* gA = Xb + (size_t)(bm0 + trow) * D_ + 8 * tcg;
    const u16* gB = Wt + (size_t)(bn0 + trow) * D_ + 8 * tcg;

    f32x4 acc[4][4];
#pragma unroll
    for (int i = 0; i < 4; i++)
#pragma unroll
        for (int j = 0; j < 4; j++) acc[i][j] = (f32x4)0.0f;

    for (int k0 = 0; k0 < D_; k0 += 64) {
#pragma unroll
        for (int i = 0; i < 4; i++) {
            gload16(gA + (size_t)(32 * i) * D_ + k0, &As[0][0] + 512 * w + 2048 * i);
            gload16(gB + (size_t)(32 * i) * D_ + k0, &Bs[0][0] + 512 * w + 2048 * i);
        }
        __syncthreads();
#pragma unroll
        for (int kk = 0; kk < 2; kk++) {
            bf16x8 a[4], b[4];
#pragma unroll
            for (int mi = 0; mi < 4; mi++)
                a[mi] = *(const bf16x8*)&As[wr * 64 + 16 * mi + c][8 * ((4 * kk + g) ^ (c & 7))];
#pragma unroll
            for (int ni = 0; ni < 4; ni++)
                b[ni] = *(const bf16x8*)&Bs[wc * 64 + 16 * ni + c][8 * ((4 * kk + g) ^ (c & 7))];
#pragma unroll
            for (int mi = 0; mi < 4; mi++)
#pragma unroll
                for (int ni = 0; ni < 4; ni++)
                    acc[mi][ni] = __builtin_amdgcn_mfma_f32_16x16x32_bf16(a[mi], b[ni], acc[mi][ni], 0, 0, 0);
        }
        __syncthreads();
    }
#pragma unroll
    for (int mi = 0; mi < 4; mi++)
#pragma unroll
        for (int ni = 0; ni < 4; ni++)
#pragma unroll
            for (int r = 0; r < 4; r++) {
                int m = bm0 + wr * 64 + 16 * mi + 4 * g + r;
                int n = bn0 + wc * 64 + 16 * ni + c;
                float v = (acc[mi][ni][r] + bias[n]) * oscale;
                int b = m >> 11, s = m & 2047;
                int h = n >> 5, dk = n & 31;
                Out[(((size_t)(b * H_ + h) * S_) + s) * DK_ + dk] = f2b(v);
            }
}

// ---------------- flash attention (r14 body + V register-prefetch one tile ahead) ----------------
// 256 q per block (8 waves x 32 q), KVBLK=128, single buffer, 2 barriers/tile,
// K via gload16 (verified inverse perm), Q pre-scaled, row-sum via ones-MFMA, setprio.
// V global loads for tile t+1 issue inside tile t's compute phase (register-only ->
// provably race-free; LDS writes stay in their r14 phase slots).
__launch_bounds__(512)
__global__ void attn_kernel(const u16* __restrict__ Q, const u16* __restrict__ K,
                            const u16* __restrict__ V, u16* __restrict__ O,
                            const int* __restrict__ mbp) {
    const int border = *mbp;
    const unsigned b2u = (unsigned)(2 * border);
    const int bh = blockIdx.x;          // all q-blocks of one bh -> same XCD (ids differ by 64)
    const int q0 = blockIdx.y * 256;
    const int tid = threadIdx.x;
    const int lane = tid & 63;
    const int w = __builtin_amdgcn_readfirstlane(tid >> 6);   // wave-uniform
    const int g = lane >> 4, c = lane & 15;

    __shared__ __attribute__((aligned(16))) u16 Ks[128][32];     // two permuted 64-row halves
    __shared__ __attribute__((aligned(16))) u16 Vt[2][32][68];   // [kv-half][dv][kk]

    const u16* Qbh = Q + (size_t)bh * S_ * DK_;
    const u16* Kbh = K + (size_t)bh * S_ * DK_;
    const u16* Vbh = V + (size_t)bh * S_ * DK_;

    const int qw0 = q0 + w * 32;        // wave-uniform
    const int qiA = qw0 + c;
    const int qiB = qw0 + 16 + c;
    const bf16x8 qfA = *(const bf16x8*)&Qbh[(size_t)qiA * DK_ + 8 * g];
    const bf16x8 qfB = *(const bf16x8*)&Qbh[(size_t)qiB * DK_ + 8 * g];

    f32x4 accO[2][2];   // [qs][dv-half]
    f32x4 accL[2];      // [qs] row-sum accumulator (all rows identical)
#pragma unroll
    for (int i = 0; i < 2; i++) { accO[i][0] = (f32x4)0.0f; accO[i][1] = (f32x4)0.0f; accL[i] = (f32x4)0.0f; }

    const float C2 = 1.4426950408889634f;   // log2(e) * 1.0 (band add, post-scale)

    // ones A-fragment for row-sum MFMA (constant -> layout-independent)
    union { u16x4 h[2]; bf16x8 v; } ones;
#pragma unroll
    for (int j = 0; j < 4; j++) { ones.h[0][j] = 0x3F80; ones.h[1][j] = 0x3F80; }

    // K staging via gload16: lane fills LDS row L = 16w + (lane>>2), granule lane&3.
    // Global row = inverse of verified forward map srow(skk)=32*b2+16*b5+4*b34+b01:
    //   inv(L) = (L&3) + 4*((L>>5)&1) + 8*((L>>2)&3) + 32*((L>>4)&1); bit6 passes through.
    const int gl_L = 16 * w + (lane >> 2);
    const int gl_gr = (gl_L & 64) + (gl_L & 3) + 4 * ((gl_L >> 5) & 1)
                    + 8 * ((gl_L >> 2) & 3) + 32 * ((gl_L >> 4) & 1);
    const u16* ksrc = Kbh + (size_t)gl_gr * DK_ + 8 * (lane & 3);
    u16* kdst = &Ks[0][0] + (w << 9);   // wave-uniform base, w*1024 bytes

    // V staging indices (round-2 verified): 512 thr x u16x4 covers one 64x32 tile
    const int skk = tid >> 3;
    const int sc4 = (tid & 7) << 2;
    const u16* vp0 = Vbh + (size_t)skk * DK_ + sc4;

    // softmax+pack for one 16-q subtile vs one 64-kv subtile
    auto sm_pack = [&](const f32x4* sf, int qs0, int qiv, int kvs, pbu* pb) {
        float e[4][4];
        const bool aOut = (qs0 > kvs + 63 + border) || (qs0 + 15 + border < kvs);
        const bool aIn  = (qs0 + 15 <= kvs + border) && (kvs + 63 <= qs0 + border);
        if (aOut) {
#pragma unroll
            for (int ct = 0; ct < 4; ct++)
#pragma unroll
                for (int r = 0; r < 4; r++)
                    e[ct][r] = __builtin_amdgcn_exp2f(sf[ct][r]);
        } else if (aIn) {
#pragma unroll
            for (int ct = 0; ct < 4; ct++)
#pragma unroll
                for (int r = 0; r < 4; r++)
                    e[ct][r] = __builtin_amdgcn_exp2f(sf[ct][r] + C2);
        } else {
            const int qb = qiv + border - kvs;
#pragma unroll
            for (int ct = 0; ct < 4; ct++) {
                const int k0l = 32 * (ct & 1) + 8 * g + 4 * (ct >> 1);
#pragma unroll
                for (int r = 0; r < 4; r++) {
                    float a = ((unsigned)(qb - (k0l + r)) <= b2u) ? C2 : 0.0f;
                    e[ct][r] = __builtin_amdgcn_exp2f(sf[ct][r] + a);
                }
            }
        }
        // pack (round-2 verified ordering)
        pb[0].u[0] = cvt_pk_bf16(e[0][0], e[0][1]);
        pb[0].u[1] = cvt_pk_bf16(e[0][2], e[0][3]);
        pb[0].u[2] = cvt_pk_bf16(e[2][0], e[2][1]);
        pb[0].u[3] = cvt_pk_bf16(e[2][2], e[2][3]);
        pb[1].u[0] = cvt_pk_bf16(e[1][0], e[1][1]);
        pb[1].u[1] = cvt_pk_bf16(e[1][2], e[1][3]);
        pb[1].u[2] = cvt_pk_bf16(e[3][0], e[3][1]);
        pb[1].u[3] = cvt_pk_bf16(e[3][2], e[3][3]);
    };

    // one 64-kv subtile: QK^T (both q-subtiles) -> softmax -> PV + row-sum MFMA
    auto do_sub = [&](int sub, int kvs) {
        f32x4 sA[4], sB[4];
#pragma unroll
        for (int ct = 0; ct < 4; ct++) {
            const bf16x8 kf = *(const bf16x8*)&Ks[sub * 64 + 16 * ct + c][8 * g];
            sA[ct] = __builtin_amdgcn_mfma_f32_16x16x32_bf16(kf, qfA, (f32x4)0.0f, 0, 0, 0);
            sB[ct] = __builtin_amdgcn_mfma_f32_16x16x32_bf16(kf, qfB, (f32x4)0.0f, 0, 0, 0);
        }
        pbu pA[2], pB[2];
        sm_pack(sA, qw0, qiA, kvs, pA);
        sm_pack(sB, qw0 + 16, qiB, kvs, pB);
#pragma unroll
        for (int t2 = 0; t2 < 2; t2++) {
#pragma unroll
            for (int ksl = 0; ksl < 2; ksl++) {
                union { u16x4 h[2]; bf16x8 v; } vf;
                vf.h[0] = *(const u16x4*)&Vt[sub][16 * t2 + c][32 * ksl + 8 * g];
                vf.h[1] = *(const u16x4*)&Vt[sub][16 * t2 + c][32 * ksl + 8 * g + 4];
                accO[0][t2] = __builtin_amdgcn_mfma_f32_16x16x32_bf16(vf.v, pA[ksl].v, accO[0][t2], 0, 0, 0);
                accO[1][t2] = __builtin_amdgcn_mfma_f32_16x16x32_bf16(vf.v, pB[ksl].v, accO[1][t2], 0, 0, 0);
            }
        }
#pragma unroll
        for (int ksl = 0; ksl < 2; ksl++) {
            accL[0] = __builtin_amdgcn_mfma_f32_16x16x32_bf16(ones.v, pA[ksl].v, accL[0], 0, 0, 0);
            accL[1] = __builtin_amdgcn_mfma_f32_16x16x32_bf16(ones.v, pB[ksl].v, accL[1], 0, 0, 0);
        }
    };

    // prologue: prefetch V for tile 0
    u16x4 va = *(const u16x4*)vp0;
    u16x4 vb = *(const u16x4*)(vp0 + 64 * DK_);

    for (int kv0 = 0; kv0 < S_; kv0 += 128) {
        // stage K (async DMA, permuted source rows) + write prefetched V registers
        gload16(ksrc + (size_t)kv0 * DK_, kdst);
#pragma unroll
        for (int j = 0; j < 4; j++) {
            Vt[0][sc4 + j][skk] = va[j];
            Vt[1][sc4 + j][skk] = vb[j];
        }
        __syncthreads();   // drains vmcnt (K gload) + lgkm (V writes)

        // issue next tile's V loads (register-only; latency hidden under compute)
        if (kv0 + 128 < S_) {
            va = *(const u16x4*)(vp0 + (size_t)(kv0 + 128) * DK_);
            vb = *(const u16x4*)(vp0 + (size_t)(kv0 + 192) * DK_);
        }

        __builtin_amdgcn_s_setprio(1);
        do_sub(0, kv0);
        do_sub(1, kv0 + 64);
        __builtin_amdgcn_s_setprio(0);

        __syncthreads();
    }

    // epilogue: l from accL (all rows equal; col c corresponds to this lane's q)
    const int b = bh >> 4, h = bh & 15;
    const float linvA = 1.0f / accL[0][0];
    const float linvB = 1.0f / accL[1][0];
#pragma unroll
    for (int t2 = 0; t2 < 2; t2++) {
        u16x4 oA, oB;
#pragma unroll
        for (int r = 0; r < 4; r++) {
            oA[r] = f2b(accO[0][t2][r] * linvA);
            oB[r] = f2b(accO[1][t2][r] * linvB);
        }
        *(u16x4*)&O[((size_t)(b * S_ + qiA) * H_ + h) * DK_ + 16 * t2 + 4 * g] = oA;
        *(u16x4*)&O[((size_t)(b * S_ + qiB) * H_ + h) * DK_ + 16 * t2 + 4 * g] = oB;
    }
}

// ---------------- output GEMM: 128x128 tile, BK=64, global_load_lds + XOR swizzle, f32 out ----------------
__launch_bounds__(256)
__global__ void gemm_out(const u16* __restrict__ Ob, const u16* __restrict__ WoT,
                         const float* __restrict__ bo, float* __restrict__ out) {
    __shared__ __attribute__((aligned(16))) u16 As[128][64];
    __shared__ __attribute__((aligned(16))) u16 Bs[128][64];

    const int tid = threadIdx.x;
    const int lane = tid & 63, w = tid >> 6;
    const int wr = w >> 1, wc = w & 1;
    const int g = lane >> 4, c = lane & 15;
    const int bm0 = blockIdx.y * 128, bn0 = blockIdx.x * 128;

    const int trow = tid >> 3;
    const int tcg = (tid & 7) ^ (trow & 7);
    const u16* gA = Ob + (size_t)(bm0 + trow) * D_ + 8 * tcg;
    const u16* gB = WoT + (size_t)(bn0 + trow) * D_ + 8 * tcg;

    f32x4 acc[4][4];
#pragma unroll
    for (int i = 0; i < 4; i++)
#pragma unroll
        for (int j = 0; j < 4; j++) acc[i][j] = (f32x4)0.0f;

    for (int k0 = 0; k0 < D_; k0 += 64) {
#pragma unroll
        for (int i = 0; i < 4; i++) {
            gload16(gA + (size_t)(32 * i) * D_ + k0, &As[0][0] + 512 * w + 2048 * i);
            gload16(gB + (size_t)(32 * i) * D_ + k0, &Bs[0][0] + 512 * w + 2048 * i);
        }
        __syncthreads();
#pragma unroll
        for (int kk = 0; kk < 2; kk++) {
            bf16x8 a[4], b[4];
#pragma unroll
            for (int mi = 0; mi < 4; mi++)
                a[mi] = *(const bf16x8*)&As[wr * 64 + 16 * mi + c][8 * ((4 * kk + g) ^ (c & 7))];
#pragma unroll
            for (int ni = 0; ni < 4; ni++)
                b[ni] = *(const bf16x8*)&Bs[wc * 64 + 16 * ni + c][8 * ((4 * kk + g) ^ (c & 7))];
#pragma unroll
            for (int mi = 0; mi < 4; mi++)
#pragma unroll
                for (int ni = 0; ni < 4; ni++)
                    acc[mi][ni] = __builtin_amdgcn_mfma_f32_16x16x32_bf16(a[mi], b[ni], acc[mi][ni], 0, 0, 0);
        }
        __syncthreads();
    }
#pragma unroll
    for (int mi = 0; mi < 4; mi++)
#pragma unroll
        for (int ni = 0; ni < 4; ni++)
#pragma unroll
            for (int r = 0; r < 4; r++) {
                int m = bm0 + wr * 64 + 16 * mi + 4 * g + r;
                int n = bn0 + wc * 64 + 16 * ni + c;
                out[(size_t)m * D_ + n] = acc[mi][ni][r] + bo[n];
            }
}

extern "C" void kernel_launch(void* const* d_in, const int* in_sizes, int n_in,
                              void* d_out, int out_size, void* d_ws, size_t ws_size,
                              hipStream_t stream) {
    const float* x  = (const float*)d_in[0];
    const float* Wq = (const float*)d_in[1];
    const float* bq = (const float*)d_in[2];
    const float* Wk = (const float*)d_in[3];
    const float* bk = (const float*)d_in[4];
    const float* Wv = (const float*)d_in[5];
    const float* bv = (const float*)d_in[6];
    const float* Wo = (const float*)d_in[7];
    const float* bo = (const float*)d_in[8];
    const int* mb   = (const int*)d_in[9];
    float* out = (float*)d_out;

    char* p = (char*)d_ws;
    u16* xb = (u16*)p; p += (size_t)MS_ * D_ * 2;
    u16* wt = (u16*)p; p += (size_t)4 * D_ * D_ * 2;
    u16* qw = (u16*)p; p += (size_t)MS_ * D_ * 2;
    u16* kw = (u16*)p; p += (size_t)MS_ * D_ * 2;
    u16* vw = (u16*)p; p += (size_t)MS_ * D_ * 2;
    u16* ow = (u16*)p; p += (size_t)MS_ * D_ * 2;

    cast_f32_to_bf16<<<4096, 256, 0, stream>>>(x, xb, MS_ * D_ / 4);
    transpose_cast<<<dim3(16, 16, 4), 256, 0, stream>>>(Wq, Wk, Wv, Wo, wt);

    gemm_qkv<<<dim3(4, 64, 3), 256, 0, stream>>>(xb, wt, bq, bk, bv, qw, kw, vw);
    attn_kernel<<<dim3(64, 8), 512, 0, stream>>>(qw, kw, vw, ow, mb);
    gemm_out<<<dim3(4, 64), 256, 0, stream>>>(ow, wt + (size_t)3 * D_ * D_, bo, out);
}

// Round 16
// 97.058 us; speedup vs baseline: 1.1130x; 1.0232x over previous
//
#include <hip/hip_runtime.h>
#include <hip/hip_bf16.h>

#define B_ 4
#define S_ 2048
#define D_ 512
#define H_ 16
#define DK_ 32
#define MS_ 8192   // B_*S_

typedef unsigned short u16;
typedef __attribute__((ext_vector_type(4))) unsigned short u16x4;
typedef __attribute__((ext_vector_type(8))) short bf16x8;
typedef __attribute__((ext_vector_type(4))) float f32x4;

union pbu { unsigned u[4]; bf16x8 v; };

__device__ __forceinline__ u16 f2b(float f) {
    union { float f; unsigned u; } uf; uf.f = f;
    unsigned u = uf.u;
    unsigned r = u + 0x7fffu + ((u >> 16) & 1u);  // RNE
    return (u16)(r >> 16);
}

__device__ __forceinline__ unsigned cvt_pk_bf16(float lo, float hi) {
    unsigned r;
    asm("v_cvt_pk_bf16_f32 %0, %1, %2" : "=v"(r) : "v"(lo), "v"(hi));
    return r;
}

// async global->LDS, 16B per lane; dst is wave-uniform base, HW adds lane*16
__device__ __forceinline__ void gload16(const u16* src, u16* dst) {
    __builtin_amdgcn_global_load_lds(
        (const __attribute__((address_space(1))) unsigned int*)src,
        (__attribute__((address_space(3))) unsigned int*)dst, 16, 0, 0);
}

// ---------------- prep: fused weight transpose+cast (blocks 0..1023) + x cast (blocks 1024..5119) ----------------
__global__ void prep(const float* __restrict__ x,
                     const float* __restrict__ Wq, const float* __restrict__ Wk,
                     const float* __restrict__ Wv, const float* __restrict__ Wo,
                     u16* __restrict__ xb, u16* __restrict__ wt) {
    const int bid = blockIdx.x;
    if (bid < 1024) {
        // transpose+cast: WT[z][n][k] = W_z[k][n]  (identical arithmetic to r15 transpose_cast)
        const int z = bid >> 8, t = bid & 255;
        const float* W = (z == 0) ? Wq : (z == 1) ? Wk : (z == 2) ? Wv : Wo;
        u16* O = wt + (size_t)z * D_ * D_;
        __shared__ float T[32][33];
        const int n0 = (t & 15) * 32, k0 = (t >> 4) * 32;
        const int tx = threadIdx.x & 31, ty = threadIdx.x >> 5;
#pragma unroll
        for (int i = 0; i < 4; i++) {
            int row = ty + 8 * i;
            T[tx][row] = W[(size_t)(k0 + row) * D_ + n0 + tx];
        }
        __syncthreads();
#pragma unroll
        for (int i = 0; i < 4; i++) {
            int row = ty + 8 * i;
            O[(size_t)(n0 + row) * D_ + k0 + tx] = f2b(T[row][tx]);
        }
    } else {
        // cast f32 -> bf16 (vectorized x4); 4096 blocks cover MS_*D_/4 exactly
        const int i = (bid - 1024) * 256 + threadIdx.x;
        f32x4 v = *(const f32x4*)(x + (size_t)i * 4);
        u16x4 o;
        o[0] = f2b(v[0]); o[1] = f2b(v[1]); o[2] = f2b(v[2]); o[3] = f2b(v[3]);
        *(u16x4*)(xb + (size_t)i * 4) = o;
    }
}

// ---------------- QKV GEMM: 128x128 tile, BK=64, global_load_lds + XOR swizzle ----------------
// Q output pre-scaled by log2(e)/sqrt(32) so attn exp2 consumes scores directly.
__launch_bounds__(256)
__global__ void gemm_qkv(const u16* __restrict__ Xb, const u16* __restrict__ WT,
                         const float* __restrict__ bq, const float* __restrict__ bk, const float* __restrict__ bv,
                         u16* __restrict__ Qw, u16* __restrict__ Kw, u16* __restrict__ Vw) {
    const int which = blockIdx.z;
    const u16* Wt = WT + (size_t)which * D_ * D_;
    const float* bias = (which == 0) ? bq : (which == 1) ? bk : bv;
    u16* Out = (which == 0) ? Qw : (which == 1) ? Kw : Vw;
    const float oscale = (which == 0) ? (float)(1.4426950408889634 / 5.656854249492381) : 1.0f;

    __shared__ __attribute__((aligned(16))) u16 As[128][64];
    __shared__ __attribute__((aligned(16))) u16 Bs[128][64];

    const int tid = threadIdx.x;
    const int lane = tid & 63, w = tid >> 6;
    const int wr = w >> 1, wc = w & 1;
    const int g = lane >> 4, c = lane & 15;
    const int bm0 = blockIdx.y * 128, bn0 = blockIdx.x * 128;

    const int trow = tid >> 3;
    const int tcg = (tid & 7) ^ (trow & 7);
    const u16* gA = Xb + (size_t)(bm0 + trow) * D_ + 8 * tcg;
    const u16* gB = Wt + (size_t)(bn0 + trow) * D_ + 8 * tcg;

    f32x4 acc[4][4];
#pragma unroll
    for (int i = 0; i < 4; i++)
#pragma unroll
        for (int j = 0; j < 4; j++) acc[i][j] = (f32x4)0.0f;

    for (int k0 = 0; k0 < D_; k0 += 64) {
#pragma unroll
        for (int i = 0; i < 4; i++) {
            gload16(gA + (size_t)(32 * i) * D_ + k0, &As[0][0] + 512 * w + 2048 * i);
            gload16(gB + (size_t)(32 * i) * D_ + k0, &Bs[0][0] + 512 * w + 2048 * i);
        }
        __syncthreads();
#pragma unroll
        for (int kk = 0; kk < 2; kk++) {
            bf16x8 a[4], b[4];
#pragma unroll
            for (int mi = 0; mi < 4; mi++)
                a[mi] = *(const bf16x8*)&As[wr * 64 + 16 * mi + c][8 * ((4 * kk + g) ^ (c & 7))];
#pragma unroll
            for (int ni = 0; ni < 4; ni++)
                b[ni] = *(const bf16x8*)&Bs[wc * 64 + 16 * ni + c][8 * ((4 * kk + g) ^ (c & 7))];
#pragma unroll
            for (int mi = 0; mi < 4; mi++)
#pragma unroll
                for (int ni = 0; ni < 4; ni++)
                    acc[mi][ni] = __builtin_amdgcn_mfma_f32_16x16x32_bf16(a[mi], b[ni], acc[mi][ni], 0, 0, 0);
        }
        __syncthreads();
    }
#pragma unroll
    for (int mi = 0; mi < 4; mi++)
#pragma unroll
        for (int ni = 0; ni < 4; ni++)
#pragma unroll
            for (int r = 0; r < 4; r++) {
                int m = bm0 + wr * 64 + 16 * mi + 4 * g + r;
                int n = bn0 + wc * 64 + 16 * ni + c;
                float v = (acc[mi][ni][r] + bias[n]) * oscale;
                int b = m >> 11, s = m & 2047;
                int h = n >> 5, dk = n & 31;
                Out[(((size_t)(b * H_ + h) * S_) + s) * DK_ + dk] = f2b(v);
            }
}

// ---------------- flash attention (r15 body + K double-buffer) ----------------
// 256 q per block (8 waves x 32 q), KVBLK=128, 2 barriers/tile, setprio.
// K via gload16 (verified inverse perm) into Ks[2] double buffer: tile t+1's DMA issues
// after BARRIER1 and drains at BARRIER2 (compiler vmcnt(0) before s_barrier), so
// BARRIER1 no longer exposes K's HBM latency. V single-buffered, reg-prefetched (r15).
__launch_bounds__(512)
__global__ void attn_kernel(const u16* __restrict__ Q, const u16* __restrict__ K,
                            const u16* __restrict__ V, u16* __restrict__ O,
                            const int* __restrict__ mbp) {
    const int border = *mbp;
    const unsigned b2u = (unsigned)(2 * border);
    const int bh = blockIdx.x;          // all q-blocks of one bh -> same XCD (ids differ by 64)
    const int q0 = blockIdx.y * 256;
    const int tid = threadIdx.x;
    const int lane = tid & 63;
    const int w = __builtin_amdgcn_readfirstlane(tid >> 6);   // wave-uniform
    const int g = lane >> 4, c = lane & 15;

    __shared__ __attribute__((aligned(16))) u16 Ks[2][128][32];  // double-buffered permuted K
    __shared__ __attribute__((aligned(16))) u16 Vt[2][32][68];   // [kv-half][dv][kk]

    const u16* Qbh = Q + (size_t)bh * S_ * DK_;
    const u16* Kbh = K + (size_t)bh * S_ * DK_;
    const u16* Vbh = V + (size_t)bh * S_ * DK_;

    const int qw0 = q0 + w * 32;        // wave-uniform
    const int qiA = qw0 + c;
    const int qiB = qw0 + 16 + c;
    const bf16x8 qfA = *(const bf16x8*)&Qbh[(size_t)qiA * DK_ + 8 * g];
    const bf16x8 qfB = *(const bf16x8*)&Qbh[(size_t)qiB * DK_ + 8 * g];

    f32x4 accO[2][2];   // [qs][dv-half]
    f32x4 accL[2];      // [qs] row-sum accumulator (all rows identical)
#pragma unroll
    for (int i = 0; i < 2; i++) { accO[i][0] = (f32x4)0.0f; accO[i][1] = (f32x4)0.0f; accL[i] = (f32x4)0.0f; }

    const float C2 = 1.4426950408889634f;   // log2(e) * 1.0 (band add, post-scale)

    // ones A-fragment for row-sum MFMA (constant -> layout-independent)
    union { u16x4 h[2]; bf16x8 v; } ones;
#pragma unroll
    for (int j = 0; j < 4; j++) { ones.h[0][j] = 0x3F80; ones.h[1][j] = 0x3F80; }

    // K staging via gload16: lane fills LDS row L = 16w + (lane>>2), granule lane&3.
    // Global row = inverse of verified forward map srow(skk)=32*b2+16*b5+4*b34+b01:
    //   inv(L) = (L&3) + 4*((L>>5)&1) + 8*((L>>2)&3) + 32*((L>>4)&1); bit6 passes through.
    const int gl_L = 16 * w + (lane >> 2);
    const int gl_gr = (gl_L & 64) + (gl_L & 3) + 4 * ((gl_L >> 5) & 1)
                    + 8 * ((gl_L >> 2) & 3) + 32 * ((gl_L >> 4) & 1);
    const u16* ksrc = Kbh + (size_t)gl_gr * DK_ + 8 * (lane & 3);
    u16* kb0 = &Ks[0][0][0] + (w << 9);   // wave-uniform bases, w*1024 bytes
    u16* kb1 = &Ks[1][0][0] + (w << 9);

    // V staging indices (round-2 verified): 512 thr x u16x4 covers one 64x32 tile
    const int skk = tid >> 3;
    const int sc4 = (tid & 7) << 2;
    const u16* vp0 = Vbh + (size_t)skk * DK_ + sc4;

    // softmax+pack for one 16-q subtile vs one 64-kv subtile
    auto sm_pack = [&](const f32x4* sf, int qs0, int qiv, int kvs, pbu* pb) {
        float e[4][4];
        const bool aOut = (qs0 > kvs + 63 + border) || (qs0 + 15 + border < kvs);
        const bool aIn  = (qs0 + 15 <= kvs + border) && (kvs + 63 <= qs0 + border);
        if (aOut) {
#pragma unroll
            for (int ct = 0; ct < 4; ct++)
#pragma unroll
                for (int r = 0; r < 4; r++)
                    e[ct][r] = __builtin_amdgcn_exp2f(sf[ct][r]);
        } else if (aIn) {
#pragma unroll
            for (int ct = 0; ct < 4; ct++)
#pragma unroll
                for (int r = 0; r < 4; r++)
                    e[ct][r] = __builtin_amdgcn_exp2f(sf[ct][r] + C2);
        } else {
            const int qb = qiv + border - kvs;
#pragma unroll
            for (int ct = 0; ct < 4; ct++) {
                const int k0l = 32 * (ct & 1) + 8 * g + 4 * (ct >> 1);
#pragma unroll
                for (int r = 0; r < 4; r++) {
                    float a = ((unsigned)(qb - (k0l + r)) <= b2u) ? C2 : 0.0f;
                    e[ct][r] = __builtin_amdgcn_exp2f(sf[ct][r] + a);
                }
            }
        }
        // pack (round-2 verified ordering)
        pb[0].u[0] = cvt_pk_bf16(e[0][0], e[0][1]);
        pb[0].u[1] = cvt_pk_bf16(e[0][2], e[0][3]);
        pb[0].u[2] = cvt_pk_bf16(e[2][0], e[2][1]);
        pb[0].u[3] = cvt_pk_bf16(e[2][2], e[2][3]);
        pb[1].u[0] = cvt_pk_bf16(e[1][0], e[1][1]);
        pb[1].u[1] = cvt_pk_bf16(e[1][2], e[1][3]);
        pb[1].u[2] = cvt_pk_bf16(e[3][0], e[3][1]);
        pb[1].u[3] = cvt_pk_bf16(e[3][2], e[3][3]);
    };

    // one 64-kv subtile from K buffer Kb: QK^T (both q-subtiles) -> softmax -> PV + row-sum MFMA
    auto do_sub = [&](const u16 (*Kb)[32], int sub, int kvs) {
        f32x4 sA[4], sB[4];
#pragma unroll
        for (int ct = 0; ct < 4; ct++) {
            const bf16x8 kf = *(const bf16x8*)&Kb[sub * 64 + 16 * ct + c][8 * g];
            sA[ct] = __builtin_amdgcn_mfma_f32_16x16x32_bf16(kf, qfA, (f32x4)0.0f, 0, 0, 0);
            sB[ct] = __builtin_amdgcn_mfma_f32_16x16x32_bf16(kf, qfB, (f32x4)0.0f, 0, 0, 0);
        }
        pbu pA[2], pB[2];
        sm_pack(sA, qw0, qiA, kvs, pA);
        sm_pack(sB, qw0 + 16, qiB, kvs, pB);
#pragma unroll
        for (int t2 = 0; t2 < 2; t2++) {
#pragma unroll
            for (int ksl = 0; ksl < 2; ksl++) {
                union { u16x4 h[2]; bf16x8 v; } vf;
                vf.h[0] = *(const u16x4*)&Vt[sub][16 * t2 + c][32 * ksl + 8 * g];
                vf.h[1] = *(const u16x4*)&Vt[sub][16 * t2 + c][32 * ksl + 8 * g + 4];
                accO[0][t2] = __builtin_amdgcn_mfma_f32_16x16x32_bf16(vf.v, pA[ksl].v, accO[0][t2], 0, 0, 0);
                accO[1][t2] = __builtin_amdgcn_mfma_f32_16x16x32_bf16(vf.v, pB[ksl].v, accO[1][t2], 0, 0, 0);
            }
        }
#pragma unroll
        for (int ksl = 0; ksl < 2; ksl++) {
            accL[0] = __builtin_amdgcn_mfma_f32_16x16x32_bf16(ones.v, pA[ksl].v, accL[0], 0, 0, 0);
            accL[1] = __builtin_amdgcn_mfma_f32_16x16x32_bf16(ones.v, pB[ksl].v, accL[1], 0, 0, 0);
        }
    };

    // prologue: stage K tile 0 into buffer 0; prefetch V regs for tile 0
    gload16(ksrc, kb0);
    u16x4 va = *(const u16x4*)vp0;
    u16x4 vb = *(const u16x4*)(vp0 + 64 * DK_);

    int cur = 0;
    for (int kv0 = 0; kv0 < S_; kv0 += 128) {
        // write prefetched V registers for this tile
#pragma unroll
        for (int j = 0; j < 4; j++) {
            Vt[0][sc4 + j][skk] = va[j];
            Vt[1][sc4 + j][skk] = vb[j];
        }
        __syncthreads();   // BARRIER1: V(t) LDS-visible; K(t) DMA already drained (prologue/BARRIER2)

        // issue next tile's K DMA into the other buffer + V register prefetch
        // (drained by BARRIER2's vmcnt(0); whole compute phase hides the latency)
        if (kv0 + 128 < S_) {
            gload16(ksrc + (size_t)(kv0 + 128) * DK_, cur ? kb0 : kb1);
            va = *(const u16x4*)(vp0 + (size_t)(kv0 + 128) * DK_);
            vb = *(const u16x4*)(vp0 + (size_t)(kv0 + 192) * DK_);
        }

        const u16 (*Kb)[32] = Ks[cur];
        __builtin_amdgcn_s_setprio(1);
        do_sub(Kb, 0, kv0);
        do_sub(Kb, 1, kv0 + 64);
        __builtin_amdgcn_s_setprio(0);

        __syncthreads();   // BARRIER2: compute done (Vt reusable), K(t+1) DMA drained
        cur ^= 1;
    }

    // epilogue: l from accL (all rows equal; col c corresponds to this lane's q)
    const int b = bh >> 4, h = bh & 15;
    const float linvA = 1.0f / accL[0][0];
    const float linvB = 1.0f / accL[1][0];
#pragma unroll
    for (int t2 = 0; t2 < 2; t2++) {
        u16x4 oA, oB;
#pragma unroll
        for (int r = 0; r < 4; r++) {
            oA[r] = f2b(accO[0][t2][r] * linvA);
            oB[r] = f2b(accO[1][t2][r] * linvB);
        }
        *(u16x4*)&O[((size_t)(b * S_ + qiA) * H_ + h) * DK_ + 16 * t2 + 4 * g] = oA;
        *(u16x4*)&O[((size_t)(b * S_ + qiB) * H_ + h) * DK_ + 16 * t2 + 4 * g] = oB;
    }
}

// ---------------- output GEMM: 128x128 tile, BK=64, global_load_lds + XOR swizzle, f32 out ----------------
__launch_bounds__(256)
__global__ void gemm_out(const u16* __restrict__ Ob, const u16* __restrict__ WoT,
                         const float* __restrict__ bo, float* __restrict__ out) {
    __shared__ __attribute__((aligned(16))) u16 As[128][64];
    __shared__ __attribute__((aligned(16))) u16 Bs[128][64];

    const int tid = threadIdx.x;
    const int lane = tid & 63, w = tid >> 6;
    const int wr = w >> 1, wc = w & 1;
    const int g = lane >> 4, c = lane & 15;
    const int bm0 = blockIdx.y * 128, bn0 = blockIdx.x * 128;

    const int trow = tid >> 3;
    const int tcg = (tid & 7) ^ (trow & 7);
    const u16* gA = Ob + (size_t)(bm0 + trow) * D_ + 8 * tcg;
    const u16* gB = WoT + (size_t)(bn0 + trow) * D_ + 8 * tcg;

    f32x4 acc[4][4];
#pragma unroll
    for (int i = 0; i < 4; i++)
#pragma unroll
        for (int j = 0; j < 4; j++) acc[i][j] = (f32x4)0.0f;

    for (int k0 = 0; k0 < D_; k0 += 64) {
#pragma unroll
        for (int i = 0; i < 4; i++) {
            gload16(gA + (size_t)(32 * i) * D_ + k0, &As[0][0] + 512 * w + 2048 * i);
            gload16(gB + (size_t)(32 * i) * D_ + k0, &Bs[0][0] + 512 * w + 2048 * i);
        }
        __syncthreads();
#pragma unroll
        for (int kk = 0; kk < 2; kk++) {
            bf16x8 a[4], b[4];
#pragma unroll
            for (int mi = 0; mi < 4; mi++)
                a[mi] = *(const bf16x8*)&As[wr * 64 + 16 * mi + c][8 * ((4 * kk + g) ^ (c & 7))];
#pragma unroll
            for (int ni = 0; ni < 4; ni++)
                b[ni] = *(const bf16x8*)&Bs[wc * 64 + 16 * ni + c][8 * ((4 * kk + g) ^ (c & 7))];
#pragma unroll
            for (int mi = 0; mi < 4; mi++)
#pragma unroll
                for (int ni = 0; ni < 4; ni++)
                    acc[mi][ni] = __builtin_amdgcn_mfma_f32_16x16x32_bf16(a[mi], b[ni], acc[mi][ni], 0, 0, 0);
        }
        __syncthreads();
    }
#pragma unroll
    for (int mi = 0; mi < 4; mi++)
#pragma unroll
        for (int ni = 0; ni < 4; ni++)
#pragma unroll
            for (int r = 0; r < 4; r++) {
                int m = bm0 + wr * 64 + 16 * mi + 4 * g + r;
                int n = bn0 + wc * 64 + 16 * ni + c;
                out[(size_t)m * D_ + n] = acc[mi][ni][r] + bo[n];
            }
}

extern "C" void kernel_launch(void* const* d_in, const int* in_sizes, int n_in,
                              void* d_out, int out_size, void* d_ws, size_t ws_size,
                              hipStream_t stream) {
    const float* x  = (const float*)d_in[0];
    const float* Wq = (const float*)d_in[1];
    const float* bq = (const float*)d_in[2];
    const float* Wk = (const float*)d_in[3];
    const float* bk = (const float*)d_in[4];
    const float* Wv = (const float*)d_in[5];
    const float* bv = (const float*)d_in[6];
    const float* Wo = (const float*)d_in[7];
    const float* bo = (const float*)d_in[8];
    const int* mb   = (const int*)d_in[9];
    float* out = (float*)d_out;

    char* p = (char*)d_ws;
    u16* xb = (u16*)p; p += (size_t)MS_ * D_ * 2;
    u16* wt = (u16*)p; p += (size_t)4 * D_ * D_ * 2;
    u16* qw = (u16*)p; p += (size_t)MS_ * D_ * 2;
    u16* kw = (u16*)p; p += (size_t)MS_ * D_ * 2;
    u16* vw = (u16*)p; p += (size_t)MS_ * D_ * 2;
    u16* ow = (u16*)p; p += (size_t)MS_ * D_ * 2;

    prep<<<5120, 256, 0, stream>>>(x, Wq, Wk, Wv, Wo, xb, wt);

    gemm_qkv<<<dim3(4, 64, 3), 256, 0, stream>>>(xb, wt, bq, bk, bv, qw, kw, vw);
    attn_kernel<<<dim3(64, 8), 512, 0, stream>>>(qw, kw, vw, ow, mb);
    gemm_out<<<dim3(4, 64), 256, 0, stream>>>(ow, wt + (size_t)3 * D_ * D_, bo, out);
}